// Round 15
// baseline (103.687 us; speedup 1.0000x reference)
//
#include <hip/hip_runtime.h>
#include <math.h>

#define BS   16
#define PP   2048
#define CIN  500
#define NROW (BS * PP)            // 32768
#define JQ   256                  // j's per iou block
#define NQ   8                    // j slices
#define IT   256                  // i's per iou block (4 slots/lane)
#define NIT  8                    // i tiles per batch
#define NBLK_IOU (BS * NIT * NQ)  // 1024
#define NBT2 128
#define HIMASK 0xFFFFF800u

typedef int v8i __attribute__((ext_vector_type(8)));

// ---------------------------------------------------------------------------
// K1: cand — per (b,c): cand = score>0.5, fallback to first-argmax one-hot
// when count<=1. Writes cmask[(b*3+c)*PP + j] = 0/1.
// ---------------------------------------------------------------------------
__global__ void __launch_bounds__(256) cand_kernel(
    const float* __restrict__ pre_score, unsigned* __restrict__ cmask)
{
    int bc = blockIdx.x;          // b*3 + c
    int b = bc / 3, c = bc - b * 3;
    int tid = threadIdx.x;
    __shared__ float sv[256];
    __shared__ int   si[256];
    __shared__ int   sn[256];

    float v[8];
#pragma unroll
    for (int t = 0; t < 8; ++t) {
        int j = t * 256 + tid;
        v[t] = pre_score[((size_t)b * PP + j) * 3 + c];
    }
    float bv = -1.0f; int bi = 0; int cnt = 0;
#pragma unroll
    for (int t = 0; t < 8; ++t) {
        int j = t * 256 + tid;
        if (v[t] > 0.5f) cnt++;
        if (v[t] > bv) { bv = v[t]; bi = j; }   // strict > => first max
    }
    sv[tid] = bv; si[tid] = bi; sn[tid] = cnt;
    __syncthreads();
    for (int s2 = 128; s2 > 0; s2 >>= 1) {
        if (tid < s2) {
            float ov = sv[tid + s2]; int oi = si[tid + s2];
            if (ov > sv[tid] || (ov == sv[tid] && oi < si[tid])) { sv[tid] = ov; si[tid] = oi; }
            sn[tid] += sn[tid + s2];
        }
        __syncthreads();
    }
    int total = sn[0];
    int amax  = si[0];
#pragma unroll
    for (int t = 0; t < 8; ++t) {
        int j = t * 256 + tid;
        bool cb = (total <= 1) ? (j == amax) : (v[t] > 0.5f);
        cmask[(size_t)bc * PP + j] = cb ? 1u : 0u;
    }
}

// ---------------------------------------------------------------------------
// K2: sortpack — one block per batch. Bitonic-sort keys (truncated x1 | j)
// in LDS (any permutation is semantically correct: masks embed orig j, max
// is order-insensitive). Write sorted 32-B records {x1,y1,x2,y2,area,
// m0,m1,m2} with m_c = cand ? (0xFFFFF800 | (2047-orig_j)) : 0, perm
// (sorted pos -> orig j), and per-tile (tmin_x1_lb, max_x2) bounds.
// ---------------------------------------------------------------------------
__global__ void __launch_bounds__(512) sortpack_kernel(
    const float* __restrict__ rois, const unsigned* __restrict__ cmask,
    uint4* __restrict__ rec2, int* __restrict__ perm,
    float2* __restrict__ tileinfo)
{
    __shared__ unsigned skey[PP];   // 8 KiB
    __shared__ float    sx2[PP];    // 8 KiB
    int b = blockIdx.x;
    int tid = threadIdx.x;
    const float4* rb = (const float4*)(rois + (size_t)b * PP * 4);

    for (int p = tid; p < PP; p += 512)
        skey[p] = (__float_as_uint(rb[p].x) & 0xFFFFF800u) | (unsigned)p;
    __syncthreads();

    for (unsigned k = 2; k <= PP; k <<= 1) {
        for (unsigned jj = k >> 1; jj > 0; jj >>= 1) {
            for (int p = tid; p < PP; p += 512) {
                unsigned ixj = (unsigned)p ^ jj;
                if (ixj > (unsigned)p) {
                    unsigned a = skey[p], b2 = skey[ixj];
                    bool up = ((p & k) == 0);
                    if ((a > b2) == up) { skey[p] = b2; skey[ixj] = a; }
                }
            }
            __syncthreads();
        }
    }

    float tminr = 0.f;
    if (tid < 8) tminr = __uint_as_float(skey[tid * 256] & 0xFFFFF800u);

    for (int t = 0; t < 4; ++t) {
        int p = t * 512 + tid;
        unsigned o = skey[p] & 0x7FFu;
        float4 bx = rb[o];
        sx2[p] = bx.z;
        float area = (bx.z - bx.x) * (bx.w - bx.y);
        unsigned jfm = 0xFFFFF800u | (2047u - o);
        unsigned c0 = cmask[((size_t)b * 3 + 0) * PP + o];
        unsigned c1 = cmask[((size_t)b * 3 + 1) * PP + o];
        unsigned c2 = cmask[((size_t)b * 3 + 2) * PP + o];
        uint4 lo, hi;
        lo.x = __float_as_uint(bx.x);
        lo.y = __float_as_uint(bx.y);
        lo.z = __float_as_uint(bx.z);
        lo.w = __float_as_uint(bx.w);
        hi.x = __float_as_uint(area);
        hi.y = c0 ? jfm : 0u;
        hi.z = c1 ? jfm : 0u;
        hi.w = c2 ? jfm : 0u;
        rec2[((size_t)b * PP + p) * 2 + 0] = lo;
        rec2[((size_t)b * PP + p) * 2 + 1] = hi;
        perm[(size_t)b * PP + p] = (int)o;
    }
    __syncthreads();
    // per-tile max x2 (8 segments of 256)
    for (int s = 128; s > 0; s >>= 1) {
        for (int t2 = tid; t2 < 8 * s; t2 += 512) {
            int seg = t2 / s, off = t2 - seg * s;
            int base = seg * 256 + off;
            float a2 = sx2[base], b2 = sx2[base + s];
            sx2[base] = a2 > b2 ? a2 : b2;
        }
        __syncthreads();
    }
    if (tid < 8)
        tileinfo[b * 8 + tid] = make_float2(tminr, sx2[tid * 256]);
}

// ---------------------------------------------------------------------------
// K3: fused iou + fc_softmax. 512 thr (8 waves) cover 256 sorted i's (4
// slots/lane) x 256 sorted j's (SMEM s_load_dwordx8 broadcast, batches of 4,
// double-buffered). Wave-uniform x-interval skip per j (sorted order =>
// ~45% of j's provably IoU=0 vs the tile). Packed-key argmax: key =
// (iou & HIMASK) | (2047-orig_j) via masks; exact first-max tie-break in any
// order. fc: reg-held weights + prefetched input rows (no LDS, no conflicts).
// ---------------------------------------------------------------------------
__global__ void __launch_bounds__(512, 4) fused_kernel(
    const unsigned* __restrict__ rec2d, const float2* __restrict__ tileinfo,
    unsigned* __restrict__ qres,
    const float* __restrict__ inputs, const float* __restrict__ fc_w,
    const float* __restrict__ fc_b, float* __restrict__ out)
{
    __shared__ unsigned bestA[3][8][IT];  // 24 KiB
    int bid = blockIdx.x;
    int q   = bid & 7;
    int it  = (bid >> 3) & 7;
    int b   = bid >> 6;
    int tid = threadIdx.x, lane = tid & 63;
    int w   = __builtin_amdgcn_readfirstlane(tid >> 6);   // wave-uniform -> SGPR

    // ---- fc operands: per-lane weight registers + input prefetch ----
    float4 wr[4][2];
#pragma unroll
    for (int c = 0; c < 4; ++c) {
        const float4* wrow = (const float4*)(fc_w + c * CIN);
        wr[c][0] = wrow[lane];
        wr[c][1] = (lane < 61) ? wrow[64 + lane]
                               : make_float4(0.f, 0.f, 0.f, 0.f);
    }
    int row0 = bid * 32 + w * 4;
    int f1 = (lane < 61) ? 64 + lane : 0;   // clamped; weight=0 kills lanes>=61
    float4 xin[4][2];
#pragma unroll
    for (int r = 0; r < 4; ++r) {
        const float4* in4 = (const float4*)(inputs + (size_t)(row0 + r) * CIN);
        xin[r][0] = in4[lane];
        xin[r][1] = in4[f1];
    }

    // ---- i-slots from sorted records ----
    const uint4* rbase2 = (const uint4*)rec2d + (size_t)b * PP * 2;
    float4 bx[4];
    float  ax[4];
#pragma unroll
    for (int s = 0; s < 4; ++s) {
        uint4 lo = rbase2[(size_t)(it * IT + s * 64 + lane) * 2];
        bx[s] = make_float4(__uint_as_float(lo.x), __uint_as_float(lo.y),
                            __uint_as_float(lo.z), __uint_as_float(lo.w));
        ax[s] = (bx[s].z - bx[s].x) * (bx[s].w - bx[s].y);
    }

    float2 ti = tileinfo[(b << 3) | it];
    float tmin = ti.x, tmax = ti.y;

    int jb = q * JQ + w * 32;                      // uniform (sorted positions)
    unsigned long long addr = (unsigned long long)rec2d
                            + (unsigned long long)(b * PP + jb) * 32ull;

    unsigned best[4][3];
#pragma unroll
    for (int s = 0; s < 4; ++s) { best[s][0] = 0u; best[s][1] = 0u; best[s][2] = 0u; }

    v8i A0, A1, A2, A3, B0, B1, B2, B3;

#define ISSUE4(R0, R1, R2, R3)                                                 \
    asm volatile("s_load_dwordx8 %0, %1, 0x0"  : "=&s"(R0) : "s"(addr));       \
    asm volatile("s_load_dwordx8 %0, %1, 0x20" : "=&s"(R1) : "s"(addr));       \
    asm volatile("s_load_dwordx8 %0, %1, 0x40" : "=&s"(R2) : "s"(addr));       \
    asm volatile("s_load_dwordx8 %0, %1, 0x60" : "=&s"(R3) : "s"(addr));       \
    addr += 128;

#define DO_J(R)                                                                \
    {                                                                          \
        float bjx = __uint_as_float((unsigned)R[0]);                           \
        float bjz = __uint_as_float((unsigned)R[2]);                           \
        if (!(bjx > tmax || bjz < tmin)) {                                     \
            float bjy = __uint_as_float((unsigned)R[1]);                       \
            float bjw = __uint_as_float((unsigned)R[3]);                       \
            float aj  = __uint_as_float((unsigned)R[4]);                       \
            unsigned m0 = (unsigned)R[5], m1 = (unsigned)R[6];                 \
            unsigned m2 = (unsigned)R[7];                                      \
            unsigned jfx = (m0 | m1 | m2) & 0x7FFu;                            \
            _Pragma("unroll")                                                  \
            for (int s = 0; s < 4; ++s) {                                      \
                float lx = fmaxf(bx[s].x, bjx), ly = fmaxf(bx[s].y, bjy);      \
                float rx = fminf(bx[s].z, bjz), ry = fminf(bx[s].w, bjw);      \
                float ww = fmaxf(rx - lx, 0.f), hh = fmaxf(ry - ly, 0.f);      \
                float inter = ww * hh;                                         \
                float uni   = (ax[s] + aj) - inter;                            \
                float iou   = inter * __builtin_amdgcn_rcpf(uni);              \
                unsigned pk = (__float_as_uint(iou) & HIMASK) | jfx;           \
                unsigned k0 = pk & m0, k1 = pk & m1, k2 = pk & m2;             \
                best[s][0] = best[s][0] > k0 ? best[s][0] : k0;                \
                best[s][1] = best[s][1] > k1 ? best[s][1] : k1;                \
                best[s][2] = best[s][2] > k2 ? best[s][2] : k2;                \
            }                                                                  \
        }                                                                      \
    }

#define BATCH(C0, C1, C2, C3, N0, N1, N2, N3, DOISSUE)                         \
    asm volatile("s_waitcnt lgkmcnt(0)"                                        \
                 : "+s"(C0), "+s"(C1), "+s"(C2), "+s"(C3));                    \
    __builtin_amdgcn_sched_barrier(0);                                         \
    if (DOISSUE) { ISSUE4(N0, N1, N2, N3) }                                    \
    DO_J(C0) DO_J(C1) DO_J(C2) DO_J(C3)

    ISSUE4(A0, A1, A2, A3)
    BATCH(A0, A1, A2, A3, B0, B1, B2, B3, 1)
    BATCH(B0, B1, B2, B3, A0, A1, A2, A3, 1)
    BATCH(A0, A1, A2, A3, B0, B1, B2, B3, 1)
    BATCH(B0, B1, B2, B3, A0, A1, A2, A3, 1)
    BATCH(A0, A1, A2, A3, B0, B1, B2, B3, 1)
    BATCH(B0, B1, B2, B3, A0, A1, A2, A3, 1)
    BATCH(A0, A1, A2, A3, B0, B1, B2, B3, 1)
    BATCH(B0, B1, B2, B3, A0, A1, A2, A3, 0)

#undef BATCH
#undef DO_J
#undef ISSUE4

#pragma unroll
    for (int s = 0; s < 4; ++s) {
        bestA[0][w][s * 64 + lane] = best[s][0];
        bestA[1][w][s * 64 + lane] = best[s][1];
        bestA[2][w][s * 64 + lane] = best[s][2];
    }
    __syncthreads();

    if (tid < IT) {
#pragma unroll
        for (int c = 0; c < 3; ++c) {
            unsigned m = bestA[c][0][tid];
#pragma unroll
            for (int w2 = 1; w2 < 8; ++w2) {
                unsigned o = bestA[c][w2][tid];
                m = m > o ? m : o;
            }
            qres[(((size_t)b * NQ + q) * 3 + c) * PP + it * IT + tid] = m;
        }
    }

    // ---- fc softmax tail: all operands already in registers ----
#pragma unroll
    for (int r = 0; r < 4; ++r) {
        float a0 = 0.f, a1 = 0.f, a2 = 0.f, a3 = 0.f;
#pragma unroll
        for (int t = 0; t < 2; ++t) {
            float4 x = xin[r][t];
            a0 += x.x * wr[0][t].x + x.y * wr[0][t].y + x.z * wr[0][t].z + x.w * wr[0][t].w;
            a1 += x.x * wr[1][t].x + x.y * wr[1][t].y + x.z * wr[1][t].z + x.w * wr[1][t].w;
            a2 += x.x * wr[2][t].x + x.y * wr[2][t].y + x.z * wr[2][t].z + x.w * wr[2][t].w;
            a3 += x.x * wr[3][t].x + x.y * wr[3][t].y + x.z * wr[3][t].z + x.w * wr[3][t].w;
        }
#pragma unroll
        for (int off = 32; off > 0; off >>= 1) {
            a0 += __shfl_xor(a0, off);
            a1 += __shfl_xor(a1, off);
            a2 += __shfl_xor(a2, off);
            a3 += __shfl_xor(a3, off);
        }
        if (lane == 0) {
            a0 += fc_b[0]; a1 += fc_b[1]; a2 += fc_b[2]; a3 += fc_b[3];
            float m = fmaxf(fmaxf(a0, a1), fmaxf(a2, a3));
            float e0 = expf(a0 - m), e1 = expf(a1 - m);
            float e2 = expf(a2 - m), e3 = expf(a3 - m);
            float inv = 1.0f / (e0 + e1 + e2 + e3);
            ((float4*)out)[row0 + r] = make_float4(e0 * inv, e1 * inv, e2 * inv, e3 * inv);
        }
    }
}

// ---------------------------------------------------------------------------
// K4: merge j-slices + sequential class logic + focal loss (row = perm[pos]);
// per-(b,it) partial sums. 128 blocks x 256 threads.
// ---------------------------------------------------------------------------
__global__ void __launch_bounds__(256) merge_focal_kernel(
    const unsigned* __restrict__ qres, const int* __restrict__ perm,
    const float* __restrict__ pre_score, const int* __restrict__ labels,
    const float* __restrict__ xr, float* __restrict__ partials)
{
    __shared__ float redw[4], redf[4];
    int bt = blockIdx.x;
    int b = bt >> 3, it = bt & 7;
    int tid = threadIdx.x;
    int i = it * IT + tid;                 // sorted position

    float I = 0.f, wv = 0.f;
    int target = 3;
#pragma unroll
    for (int c = 0; c < 3; ++c) {
        unsigned k = 0u;
#pragma unroll
        for (int qq = 0; qq < NQ; ++qq) {
            unsigned h = qres[(((size_t)b * NQ + qq) * 3 + c) * PP + i];
            k = k > h ? k : h;   // packed keys globally unique per orig j
        }
        int   jv    = 2047 - (int)(k & 2047u);       // orig j
        float bestv = __uint_as_float(k & HIMASK);
        bestv = (labels[b * 3 + c] != 0) ? bestv : -1.0f;
        if (bestv > I) {
            wv = pre_score[((size_t)b * PP + jv) * 3 + c];
            if (bestv > 0.5f && target == 3) target = c;
            I = bestv;
        }
    }
    // focal loss on double-softmaxed scores of the ORIGINAL row
    int o = perm[(size_t)b * PP + i];
    int gi = b * PP + o;
    float4 x4 = ((const float4*)xr)[gi];
    float m = fmaxf(fmaxf(x4.x, x4.y), fmaxf(x4.z, x4.w));
    float e0 = expf(x4.x - m), e1 = expf(x4.y - m), e2 = expf(x4.z - m), e3 = expf(x4.w - m);
    float ssum = e0 + e1 + e2 + e3;
    float et = (target == 0) ? e0 : (target == 1) ? e1 : (target == 2) ? e2 : e3;
    float pt = et / ssum;
    pt = fminf(fmaxf(pt, 1e-7f), 1.0f - 1e-7f);
    float fl = -logf(pt) * (1.0f - pt) * (1.0f - pt);

    float sw = wv, sf = fl;
#pragma unroll
    for (int off = 32; off > 0; off >>= 1) {
        sw += __shfl_down(sw, off);
        sf += __shfl_down(sf, off);
    }
    if ((tid & 63) == 0) { redw[tid >> 6] = sw; redf[tid >> 6] = sf; }
    __syncthreads();
    if (tid == 0) {
        partials[bt * 2 + 0] = redw[0] + redw[1] + redw[2] + redw[3];
        partials[bt * 2 + 1] = redf[0] + redf[1] + redf[2] + redf[3];
    }
}

// ---------------------------------------------------------------------------
// K5: deterministic finalize: loss = mean(w) * mean(floss)
// ---------------------------------------------------------------------------
__global__ void __launch_bounds__(256) finalize_kernel(
    const float* __restrict__ partials, float* __restrict__ out_loss)
{
    __shared__ float swL[256], sfL[256];
    int tid = threadIdx.x;
    float sw = (tid < NBT2) ? partials[2 * tid] : 0.f;
    float sf = (tid < NBT2) ? partials[2 * tid + 1] : 0.f;
    swL[tid] = sw; sfL[tid] = sf;
    __syncthreads();
    for (int s = 128; s > 0; s >>= 1) {
        if (tid < s) { swL[tid] += swL[tid + s]; sfL[tid] += sfL[tid + s]; }
        __syncthreads();
    }
    if (tid == 0)
        out_loss[0] = (swL[0] / (float)NROW) * (sfL[0] / (float)NROW);
}

// ---------------------------------------------------------------------------
extern "C" void kernel_launch(void* const* d_in, const int* in_sizes, int n_in,
                              void* d_out, int out_size, void* d_ws, size_t ws_size,
                              hipStream_t stream)
{
    const float* inputs    = (const float*)d_in[0];
    const float* pre_score = (const float*)d_in[1];
    const int*   labels    = (const int*)d_in[2];
    const float* rois      = (const float*)d_in[3];
    // d_in[4] = num (2048, fixed)
    const float* fc_w      = (const float*)d_in[5];
    const float* fc_b      = (const float*)d_in[6];

    float* out = (float*)d_out;
    char* ws = (char*)d_ws;
    unsigned* qres     = (unsigned*)ws;                     // 3,145,728 B
    uint4*    rec2     = (uint4*)(ws + 3145728);            // 1,048,576 B
    unsigned* cmask    = (unsigned*)(ws + 4194304);         //   393,216 B
    int*      perm     = (int*)(ws + 4587520);              //   131,072 B
    float2*   tileinfo = (float2*)(ws + 4718592);           //     1,024 B
    float*    partials = (float*)(ws + 4719616);            //     1,024 B

    cand_kernel<<<BS * 3, 256, 0, stream>>>(pre_score, cmask);
    sortpack_kernel<<<BS, 512, 0, stream>>>(rois, cmask, rec2, perm, tileinfo);
    fused_kernel<<<NBLK_IOU, 512, 0, stream>>>((const unsigned*)rec2, tileinfo, qres,
                                               inputs, fc_w, fc_b, out);
    merge_focal_kernel<<<NBT2, 256, 0, stream>>>(qres, perm, pre_score, labels, out, partials);
    finalize_kernel<<<1, 256, 0, stream>>>(partials, out + (size_t)NROW * 4);
}

// Round 16
// 71.539 us; speedup vs baseline: 1.4494x; 1.4494x over previous
//
#include <hip/hip_runtime.h>
#include <math.h>

#define BS   16
#define PP   2048
#define CIN  500
#define NROW (BS * PP)            // 32768
#define JQ   256                  // j's per iou block
#define NQ   8                    // j slices
#define IT   256                  // i's per iou block (4 slots/lane)
#define NIT  8                    // i tiles per batch
#define NBLK_IOU (BS * NIT * NQ)  // 1024
#define NBT2 128
#define HIMASK 0xFFFFF800u
#define NBUCK 64

typedef int v8i __attribute__((ext_vector_type(8)));

// ---------------------------------------------------------------------------
// K1: candsort — one block per batch. (a) candidate logic for 3 classes
// (score>0.5, fallback to first-argmax one-hot when count<=1); (b) stable
// counting sort by x1 bucket (64 buckets, deterministic group-walk ranks);
// (c) write sorted 32-B records {x1,y1,x2,y2,area,m0,m1,m2} with
// m_c = cand ? (0xFFFFF800 | (2047-orig_j)) : 0, perm, and per-tile
// (min x1, max x2) bounds. Any permutation is semantically exact: masks
// embed orig j, the packed-key max is order-insensitive, bounds only gate
// provably-zero-IoU pairs.
// ---------------------------------------------------------------------------
__global__ void __launch_bounds__(512) candsort_kernel(
    const float* __restrict__ pre_score, const float* __restrict__ rois,
    uint4* __restrict__ rec2, int* __restrict__ perm,
    float2* __restrict__ tileinfo)
{
    __shared__ float sv[512];
    __shared__ int   si[512];
    __shared__ int   sn[512];
    __shared__ unsigned char  cbits[PP];
    __shared__ unsigned char  bkt[PP];
    __shared__ unsigned char  lrank[PP];
    __shared__ unsigned short hist[NBUCK][NBUCK];   // [group][bucket], 8 KiB
    __shared__ int bstart[NBUCK];
    __shared__ unsigned tmin[8], tmax[8];

    int b = blockIdx.x, tid = threadIdx.x;

    // ---- (a) candidate logic, 3 classes ----
    float v[3][4];
#pragma unroll
    for (int t = 0; t < 4; ++t) {
        int j = t * 512 + tid;
        const float* p = pre_score + ((size_t)b * PP + j) * 3;
        v[0][t] = p[0]; v[1][t] = p[1]; v[2][t] = p[2];
    }
    unsigned char mybits[4] = {0, 0, 0, 0};
    for (int c = 0; c < 3; ++c) {
        float bv = -1.f; int bi = 0; int cnt = 0;
#pragma unroll
        for (int t = 0; t < 4; ++t) {
            int j = t * 512 + tid;
            float x = v[c][t];
            if (x > 0.5f) cnt++;
            if (x > bv) { bv = x; bi = j; }     // strict > => first max in thread
        }
        sv[tid] = bv; si[tid] = bi; sn[tid] = cnt;
        __syncthreads();
        for (int s = 256; s > 0; s >>= 1) {
            if (tid < s) {
                float ov = sv[tid + s]; int oi = si[tid + s];
                if (ov > sv[tid] || (ov == sv[tid] && oi < si[tid])) { sv[tid] = ov; si[tid] = oi; }
                sn[tid] += sn[tid + s];
            }
            __syncthreads();
        }
        int total = sn[0], amax = si[0];
        __syncthreads();
#pragma unroll
        for (int t = 0; t < 4; ++t) {
            int j = t * 512 + tid;
            bool cb = (total <= 1) ? (j == amax) : (v[c][t] > 0.5f);
            if (cb) mybits[t] |= (unsigned char)(1 << c);
        }
    }
#pragma unroll
    for (int t = 0; t < 4; ++t) cbits[t * 512 + tid] = mybits[t];

    // ---- (b) stable counting sort by x1 bucket ----
    const float4* rb = (const float4*)(rois + (size_t)b * PP * 4);
#pragma unroll
    for (int t = 0; t < 4; ++t) {
        int j = t * 512 + tid;
        int bu = (int)(rb[j].x * (64.0f / 400.0f));
        bu = bu < 0 ? 0 : (bu > 63 ? 63 : bu);
        bkt[j] = (unsigned char)bu;
    }
    for (int t = tid; t < NBUCK * NBUCK; t += 512)
        ((unsigned short*)hist)[t] = 0;
    if (tid < 8) { tmin[tid] = 0x7F800000u; tmax[tid] = 0u; }
    __syncthreads();

    if (tid < 64) {             // stable walk: group tid owns elements [32t,32t+32)
        int base = tid * 32;
        for (int k2 = 0; k2 < 32; ++k2) {
            int j = base + k2;
            int bu = bkt[j];
            lrank[j] = (unsigned char)hist[tid][bu];
            hist[tid][bu]++;
        }
    }
    __syncthreads();
    if (tid < 64) {             // per-bucket prefix over groups (in place)
        int run = 0;
        for (int g = 0; g < 64; ++g) {
            int h = hist[g][tid];
            hist[g][tid] = (unsigned short)run;
            run += h;
        }
        sn[tid] = run;          // bucket totals
    }
    __syncthreads();
    if (tid == 0) {
        int run = 0;
        for (int bu = 0; bu < 64; ++bu) { bstart[bu] = run; run += sn[bu]; }
    }
    __syncthreads();

    // ---- (c) scatter records + perm + tile bounds ----
#pragma unroll
    for (int t = 0; t < 4; ++t) {
        int j = t * 512 + tid;
        int bu = bkt[j];
        int g  = j >> 5;
        int pos = bstart[bu] + (int)hist[g][bu] + (int)lrank[j];
        float4 bx = rb[j];
        float area = (bx.z - bx.x) * (bx.w - bx.y);
        unsigned jfm = 0xFFFFF800u | (2047u - (unsigned)j);
        unsigned char cb = cbits[j];
        uint4 lo, hi;
        lo.x = __float_as_uint(bx.x);
        lo.y = __float_as_uint(bx.y);
        lo.z = __float_as_uint(bx.z);
        lo.w = __float_as_uint(bx.w);
        hi.x = __float_as_uint(area);
        hi.y = (cb & 1) ? jfm : 0u;
        hi.z = (cb & 2) ? jfm : 0u;
        hi.w = (cb & 4) ? jfm : 0u;
        rec2[((size_t)b * PP + pos) * 2 + 0] = lo;
        rec2[((size_t)b * PP + pos) * 2 + 1] = hi;
        perm[(size_t)b * PP + pos] = j;
        int tile = pos >> 8;
        atomicMin(&tmin[tile], __float_as_uint(bx.x));
        atomicMax(&tmax[tile], __float_as_uint(bx.z));
    }
    __syncthreads();
    if (tid < 8)
        tileinfo[b * 8 + tid] = make_float2(__uint_as_float(tmin[tid]),
                                            __uint_as_float(tmax[tid]));
}

// ---------------------------------------------------------------------------
// K2: fused iou + fc_softmax. 512 thr (8 waves) cover 256 sorted i's (4
// slots/lane) x 256 sorted j's (SMEM s_load_dwordx8 broadcast, batches of 4,
// double-buffered). Block-level early-out when segment q and tile it are
// x-disjoint (~45% of blocks); else wave-uniform per-j x-skip. Packed-key
// argmax (key = (iou & HIMASK) | (2047-orig_j)) — exact first-max tie-break.
// fc: reg-held weights + prefetched input rows.
// ---------------------------------------------------------------------------
__global__ void __launch_bounds__(512, 4) fused_kernel(
    const unsigned* __restrict__ rec2d, const float2* __restrict__ tileinfo,
    unsigned* __restrict__ qres,
    const float* __restrict__ inputs, const float* __restrict__ fc_w,
    const float* __restrict__ fc_b, float* __restrict__ out)
{
    __shared__ unsigned bestA[3][8][IT];  // 24 KiB
    int bid = blockIdx.x;
    int q   = bid & 7;
    int it  = (bid >> 3) & 7;
    int b   = bid >> 6;
    int tid = threadIdx.x, lane = tid & 63;
    int w   = __builtin_amdgcn_readfirstlane(tid >> 6);   // wave-uniform -> SGPR

    // ---- fc operands: per-lane weight registers + input prefetch ----
    float4 wr[4][2];
#pragma unroll
    for (int c = 0; c < 4; ++c) {
        const float4* wrow = (const float4*)(fc_w + c * CIN);
        wr[c][0] = wrow[lane];
        wr[c][1] = (lane < 61) ? wrow[64 + lane]
                               : make_float4(0.f, 0.f, 0.f, 0.f);
    }
    int row0 = bid * 32 + w * 4;
    int f1 = (lane < 61) ? 64 + lane : 0;   // clamped; weight=0 kills lanes>=61
    float4 xin[4][2];
#pragma unroll
    for (int r = 0; r < 4; ++r) {
        const float4* in4 = (const float4*)(inputs + (size_t)(row0 + r) * CIN);
        xin[r][0] = in4[lane];
        xin[r][1] = in4[f1];
    }

    float2 ti = tileinfo[(b << 3) | it];
    float2 tq = tileinfo[(b << 3) | q];
    float tmin = ti.x, tmax = ti.y;
    bool disjoint = (tq.x > tmax) || (tq.y < tmin);   // block-uniform

    unsigned best[4][3];
#pragma unroll
    for (int s = 0; s < 4; ++s) { best[s][0] = 0u; best[s][1] = 0u; best[s][2] = 0u; }

    if (!disjoint) {
        // ---- i-slots from sorted records ----
        const uint4* rbase2 = (const uint4*)rec2d + (size_t)b * PP * 2;
        float4 bx[4];
        float  ax[4];
#pragma unroll
        for (int s = 0; s < 4; ++s) {
            uint4 lo = rbase2[(size_t)(it * IT + s * 64 + lane) * 2];
            bx[s] = make_float4(__uint_as_float(lo.x), __uint_as_float(lo.y),
                                __uint_as_float(lo.z), __uint_as_float(lo.w));
            ax[s] = (bx[s].z - bx[s].x) * (bx[s].w - bx[s].y);
        }

        int jb = q * JQ + w * 32;                  // uniform (sorted positions)
        unsigned long long addr = (unsigned long long)rec2d
                                + (unsigned long long)(b * PP + jb) * 32ull;

        v8i A0, A1, A2, A3, B0, B1, B2, B3;

#define ISSUE4(R0, R1, R2, R3)                                                 \
    asm volatile("s_load_dwordx8 %0, %1, 0x0"  : "=&s"(R0) : "s"(addr));       \
    asm volatile("s_load_dwordx8 %0, %1, 0x20" : "=&s"(R1) : "s"(addr));       \
    asm volatile("s_load_dwordx8 %0, %1, 0x40" : "=&s"(R2) : "s"(addr));       \
    asm volatile("s_load_dwordx8 %0, %1, 0x60" : "=&s"(R3) : "s"(addr));       \
    addr += 128;

#define DO_J(R)                                                                \
    {                                                                          \
        float bjx = __uint_as_float((unsigned)R[0]);                           \
        float bjz = __uint_as_float((unsigned)R[2]);                           \
        if (!(bjx > tmax || bjz < tmin)) {                                     \
            float bjy = __uint_as_float((unsigned)R[1]);                       \
            float bjw = __uint_as_float((unsigned)R[3]);                       \
            float aj  = __uint_as_float((unsigned)R[4]);                       \
            unsigned m0 = (unsigned)R[5], m1 = (unsigned)R[6];                 \
            unsigned m2 = (unsigned)R[7];                                      \
            unsigned jfx = (m0 | m1 | m2) & 0x7FFu;                            \
            _Pragma("unroll")                                                  \
            for (int s = 0; s < 4; ++s) {                                      \
                float lx = fmaxf(bx[s].x, bjx), ly = fmaxf(bx[s].y, bjy);      \
                float rx = fminf(bx[s].z, bjz), ry = fminf(bx[s].w, bjw);      \
                float ww = fmaxf(rx - lx, 0.f), hh = fmaxf(ry - ly, 0.f);      \
                float inter = ww * hh;                                         \
                float uni   = (ax[s] + aj) - inter;                            \
                float iou   = inter * __builtin_amdgcn_rcpf(uni);              \
                unsigned pk = (__float_as_uint(iou) & HIMASK) | jfx;           \
                unsigned k0 = pk & m0, k1 = pk & m1, k2 = pk & m2;             \
                best[s][0] = best[s][0] > k0 ? best[s][0] : k0;                \
                best[s][1] = best[s][1] > k1 ? best[s][1] : k1;                \
                best[s][2] = best[s][2] > k2 ? best[s][2] : k2;                \
            }                                                                  \
        }                                                                      \
    }

#define BATCH(C0, C1, C2, C3, N0, N1, N2, N3, DOISSUE)                         \
    asm volatile("s_waitcnt lgkmcnt(0)"                                        \
                 : "+s"(C0), "+s"(C1), "+s"(C2), "+s"(C3));                    \
    __builtin_amdgcn_sched_barrier(0);                                         \
    if (DOISSUE) { ISSUE4(N0, N1, N2, N3) }                                    \
    DO_J(C0) DO_J(C1) DO_J(C2) DO_J(C3)

        ISSUE4(A0, A1, A2, A3)
        BATCH(A0, A1, A2, A3, B0, B1, B2, B3, 1)
        BATCH(B0, B1, B2, B3, A0, A1, A2, A3, 1)
        BATCH(A0, A1, A2, A3, B0, B1, B2, B3, 1)
        BATCH(B0, B1, B2, B3, A0, A1, A2, A3, 1)
        BATCH(A0, A1, A2, A3, B0, B1, B2, B3, 1)
        BATCH(B0, B1, B2, B3, A0, A1, A2, A3, 1)
        BATCH(A0, A1, A2, A3, B0, B1, B2, B3, 1)
        BATCH(B0, B1, B2, B3, A0, A1, A2, A3, 0)

#undef BATCH
#undef DO_J
#undef ISSUE4
    }

#pragma unroll
    for (int s = 0; s < 4; ++s) {
        bestA[0][w][s * 64 + lane] = best[s][0];
        bestA[1][w][s * 64 + lane] = best[s][1];
        bestA[2][w][s * 64 + lane] = best[s][2];
    }
    __syncthreads();

    if (tid < IT) {
#pragma unroll
        for (int c = 0; c < 3; ++c) {
            unsigned m = bestA[c][0][tid];
#pragma unroll
            for (int w2 = 1; w2 < 8; ++w2) {
                unsigned o = bestA[c][w2][tid];
                m = m > o ? m : o;
            }
            qres[(((size_t)b * NQ + q) * 3 + c) * PP + it * IT + tid] = m;
        }
    }

    // ---- fc softmax tail: all operands already in registers ----
#pragma unroll
    for (int r = 0; r < 4; ++r) {
        float a0 = 0.f, a1 = 0.f, a2 = 0.f, a3 = 0.f;
#pragma unroll
        for (int t = 0; t < 2; ++t) {
            float4 x = xin[r][t];
            a0 += x.x * wr[0][t].x + x.y * wr[0][t].y + x.z * wr[0][t].z + x.w * wr[0][t].w;
            a1 += x.x * wr[1][t].x + x.y * wr[1][t].y + x.z * wr[1][t].z + x.w * wr[1][t].w;
            a2 += x.x * wr[2][t].x + x.y * wr[2][t].y + x.z * wr[2][t].z + x.w * wr[2][t].w;
            a3 += x.x * wr[3][t].x + x.y * wr[3][t].y + x.z * wr[3][t].z + x.w * wr[3][t].w;
        }
#pragma unroll
        for (int off = 32; off > 0; off >>= 1) {
            a0 += __shfl_xor(a0, off);
            a1 += __shfl_xor(a1, off);
            a2 += __shfl_xor(a2, off);
            a3 += __shfl_xor(a3, off);
        }
        if (lane == 0) {
            a0 += fc_b[0]; a1 += fc_b[1]; a2 += fc_b[2]; a3 += fc_b[3];
            float m = fmaxf(fmaxf(a0, a1), fmaxf(a2, a3));
            float e0 = expf(a0 - m), e1 = expf(a1 - m);
            float e2 = expf(a2 - m), e3 = expf(a3 - m);
            float inv = 1.0f / (e0 + e1 + e2 + e3);
            ((float4*)out)[row0 + r] = make_float4(e0 * inv, e1 * inv, e2 * inv, e3 * inv);
        }
    }
}

// ---------------------------------------------------------------------------
// K3: merge j-slices + sequential class logic + focal loss (row = perm[pos]);
// per-(b,it) partial sums. 128 blocks x 256 threads.
// ---------------------------------------------------------------------------
__global__ void __launch_bounds__(256) merge_focal_kernel(
    const unsigned* __restrict__ qres, const int* __restrict__ perm,
    const float* __restrict__ pre_score, const int* __restrict__ labels,
    const float* __restrict__ xr, float* __restrict__ partials)
{
    __shared__ float redw[4], redf[4];
    int bt = blockIdx.x;
    int b = bt >> 3, it = bt & 7;
    int tid = threadIdx.x;
    int i = it * IT + tid;                 // sorted position

    float I = 0.f, wv = 0.f;
    int target = 3;
#pragma unroll
    for (int c = 0; c < 3; ++c) {
        unsigned k = 0u;
#pragma unroll
        for (int qq = 0; qq < NQ; ++qq) {
            unsigned h = qres[(((size_t)b * NQ + qq) * 3 + c) * PP + i];
            k = k > h ? k : h;   // packed keys globally unique per orig j
        }
        int   jv    = 2047 - (int)(k & 2047u);       // orig j
        float bestv = __uint_as_float(k & HIMASK);
        bestv = (labels[b * 3 + c] != 0) ? bestv : -1.0f;
        if (bestv > I) {
            wv = pre_score[((size_t)b * PP + jv) * 3 + c];
            if (bestv > 0.5f && target == 3) target = c;
            I = bestv;
        }
    }
    // focal loss on double-softmaxed scores of the ORIGINAL row
    int o = perm[(size_t)b * PP + i];
    int gi = b * PP + o;
    float4 x4 = ((const float4*)xr)[gi];
    float m = fmaxf(fmaxf(x4.x, x4.y), fmaxf(x4.z, x4.w));
    float e0 = expf(x4.x - m), e1 = expf(x4.y - m), e2 = expf(x4.z - m), e3 = expf(x4.w - m);
    float ssum = e0 + e1 + e2 + e3;
    float et = (target == 0) ? e0 : (target == 1) ? e1 : (target == 2) ? e2 : e3;
    float pt = et / ssum;
    pt = fminf(fmaxf(pt, 1e-7f), 1.0f - 1e-7f);
    float fl = -logf(pt) * (1.0f - pt) * (1.0f - pt);

    float sw = wv, sf = fl;
#pragma unroll
    for (int off = 32; off > 0; off >>= 1) {
        sw += __shfl_down(sw, off);
        sf += __shfl_down(sf, off);
    }
    if ((tid & 63) == 0) { redw[tid >> 6] = sw; redf[tid >> 6] = sf; }
    __syncthreads();
    if (tid == 0) {
        partials[bt * 2 + 0] = redw[0] + redw[1] + redw[2] + redw[3];
        partials[bt * 2 + 1] = redf[0] + redf[1] + redf[2] + redf[3];
    }
}

// ---------------------------------------------------------------------------
// K4: deterministic finalize: loss = mean(w) * mean(floss)
// ---------------------------------------------------------------------------
__global__ void __launch_bounds__(256) finalize_kernel(
    const float* __restrict__ partials, float* __restrict__ out_loss)
{
    __shared__ float swL[256], sfL[256];
    int tid = threadIdx.x;
    float sw = (tid < NBT2) ? partials[2 * tid] : 0.f;
    float sf = (tid < NBT2) ? partials[2 * tid + 1] : 0.f;
    swL[tid] = sw; sfL[tid] = sf;
    __syncthreads();
    for (int s = 128; s > 0; s >>= 1) {
        if (tid < s) { swL[tid] += swL[tid + s]; sfL[tid] += sfL[tid + s]; }
        __syncthreads();
    }
    if (tid == 0)
        out_loss[0] = (swL[0] / (float)NROW) * (sfL[0] / (float)NROW);
}

// ---------------------------------------------------------------------------
extern "C" void kernel_launch(void* const* d_in, const int* in_sizes, int n_in,
                              void* d_out, int out_size, void* d_ws, size_t ws_size,
                              hipStream_t stream)
{
    const float* inputs    = (const float*)d_in[0];
    const float* pre_score = (const float*)d_in[1];
    const int*   labels    = (const int*)d_in[2];
    const float* rois      = (const float*)d_in[3];
    // d_in[4] = num (2048, fixed)
    const float* fc_w      = (const float*)d_in[5];
    const float* fc_b      = (const float*)d_in[6];

    float* out = (float*)d_out;
    char* ws = (char*)d_ws;
    unsigned* qres     = (unsigned*)ws;                     // 3,145,728 B
    uint4*    rec2     = (uint4*)(ws + 3145728);            // 1,048,576 B
    int*      perm     = (int*)(ws + 4194304);              //   131,072 B
    float2*   tileinfo = (float2*)(ws + 4325376);           //     1,024 B
    float*    partials = (float*)(ws + 4326400);            //     1,024 B

    candsort_kernel<<<BS, 512, 0, stream>>>(pre_score, rois, rec2, perm, tileinfo);
    fused_kernel<<<NBLK_IOU, 512, 0, stream>>>((const unsigned*)rec2, tileinfo, qres,
                                               inputs, fc_w, fc_b, out);
    merge_focal_kernel<<<NBT2, 256, 0, stream>>>(qres, perm, pre_score, labels, out, partials);
    finalize_kernel<<<1, 256, 0, stream>>>(partials, out + (size_t)NROW * 4);
}

// Round 17
// 62.360 us; speedup vs baseline: 1.6627x; 1.1472x over previous
//
#include <hip/hip_runtime.h>
#include <math.h>

#define BS   16
#define PP   2048
#define CIN  500
#define NROW (BS * PP)            // 32768
#define JQ   256                  // j's per iou block
#define NQ   8                    // j slices
#define IT   256                  // i's per iou block (4 slots/lane)
#define NIT  8                    // i tiles per batch
#define NBLK_IOU (BS * NIT * NQ)  // 1024
#define NBT2 128
#define HIMASK 0xFFFFF800u

typedef int v8i __attribute__((ext_vector_type(8)));

// ---------------------------------------------------------------------------
// K1: cand — per (b,c): cand = score>0.5, fallback to first-argmax one-hot
// when count<=1. 48 blocks (3x the parallelism of the old 16-block prep).
// ---------------------------------------------------------------------------
__global__ void __launch_bounds__(256) cand_kernel(
    const float* __restrict__ pre_score, unsigned* __restrict__ cmask)
{
    int bc = blockIdx.x;          // b*3 + c
    int b = bc / 3, c = bc - b * 3;
    int tid = threadIdx.x;
    __shared__ float sv[256];
    __shared__ int   si[256];
    __shared__ int   sn[256];

    float v[8];
#pragma unroll
    for (int t = 0; t < 8; ++t) {
        int j = t * 256 + tid;
        v[t] = pre_score[((size_t)b * PP + j) * 3 + c];
    }
    float bv = -1.0f; int bi = 0; int cnt = 0;
#pragma unroll
    for (int t = 0; t < 8; ++t) {
        int j = t * 256 + tid;
        if (v[t] > 0.5f) cnt++;
        if (v[t] > bv) { bv = v[t]; bi = j; }   // strict > => first max
    }
    sv[tid] = bv; si[tid] = bi; sn[tid] = cnt;
    __syncthreads();
    for (int s2 = 128; s2 > 0; s2 >>= 1) {
        if (tid < s2) {
            float ov = sv[tid + s2]; int oi = si[tid + s2];
            if (ov > sv[tid] || (ov == sv[tid] && oi < si[tid])) { sv[tid] = ov; si[tid] = oi; }
            sn[tid] += sn[tid + s2];
        }
        __syncthreads();
    }
    int total = sn[0];
    int amax  = si[0];
#pragma unroll
    for (int t = 0; t < 8; ++t) {
        int j = t * 256 + tid;
        bool cb = (total <= 1) ? (j == amax) : (v[t] > 0.5f);
        cmask[(size_t)bc * PP + j] = cb ? 0xFFFFFFFFu : 0u;
    }
}

// ---------------------------------------------------------------------------
// K2: pack — 128 blocks, one thread per j: build the 32-B record
// {x1,y1,x2,y2,area,m0,m1,m2}. Pure coalesced load->store.
// ---------------------------------------------------------------------------
__global__ void __launch_bounds__(256) pack_kernel(
    const float* __restrict__ rois, const unsigned* __restrict__ cmask,
    uint4* __restrict__ rec2)
{
    int blk = blockIdx.x;          // b*8 + seg
    int b = blk >> 3, seg = blk & 7;
    int j = seg * 256 + threadIdx.x;
    float4 bx = ((const float4*)(rois + (size_t)b * PP * 4))[j];
    float area = (bx.z - bx.x) * (bx.w - bx.y);
    uint4 lo, hi;
    lo.x = __float_as_uint(bx.x);
    lo.y = __float_as_uint(bx.y);
    lo.z = __float_as_uint(bx.z);
    lo.w = __float_as_uint(bx.w);
    hi.x = __float_as_uint(area);
    hi.y = cmask[((size_t)b * 3 + 0) * PP + j];
    hi.z = cmask[((size_t)b * 3 + 1) * PP + j];
    hi.w = cmask[((size_t)b * 3 + 2) * PP + j];
    rec2[((size_t)b * PP + j) * 2 + 0] = lo;
    rec2[((size_t)b * PP + j) * 2 + 1] = hi;
}

// ---------------------------------------------------------------------------
// K3: fused iou + fc_softmax (R14 structure, proven). 512 thr (8 waves) cover
// 256 i's (4 slots/lane) x 256 j's (SMEM s_load_dwordx8 broadcast, batches of
// 4, double-buffered). Packed-key argmax (key = (iou & HIMASK) | (2047-j)) —
// exact first-max tie-break. fc: reg-held weights + prefetched input rows
// (no LDS, no bank conflicts); fc HBM stream hides under j-loop VALU.
// ---------------------------------------------------------------------------
__global__ void __launch_bounds__(512, 4) fused_kernel(
    const float* __restrict__ rois, const unsigned* __restrict__ rec2d,
    unsigned* __restrict__ qres,
    const float* __restrict__ inputs, const float* __restrict__ fc_w,
    const float* __restrict__ fc_b, float* __restrict__ out)
{
    __shared__ unsigned bestA[3][8][IT];  // 24 KiB
    int bid = blockIdx.x;
    int q   = bid & 7;
    int it  = (bid >> 3) & 7;
    int b   = bid >> 6;
    int tid = threadIdx.x, lane = tid & 63;
    int w   = __builtin_amdgcn_readfirstlane(tid >> 6);   // wave-uniform -> SGPR

    // ---- fc operands: per-lane weight registers + input prefetch ----
    float4 wr[4][2];
#pragma unroll
    for (int c = 0; c < 4; ++c) {
        const float4* wrow = (const float4*)(fc_w + c * CIN);
        wr[c][0] = wrow[lane];
        wr[c][1] = (lane < 61) ? wrow[64 + lane]
                               : make_float4(0.f, 0.f, 0.f, 0.f);
    }
    int row0 = bid * 32 + w * 4;
    int f1 = (lane < 61) ? 64 + lane : 0;   // clamped; weight=0 kills lanes>=61
    float4 xin[4][2];
#pragma unroll
    for (int r = 0; r < 4; ++r) {
        const float4* in4 = (const float4*)(inputs + (size_t)(row0 + r) * CIN);
        xin[r][0] = in4[lane];
        xin[r][1] = in4[f1];
    }

    const float4* rbase = (const float4*)(rois + (size_t)b * PP * 4);
    float4 bx[4];
    float  ax[4];
#pragma unroll
    for (int s = 0; s < 4; ++s) {
        bx[s] = rbase[it * IT + s * 64 + lane];
        ax[s] = (bx[s].z - bx[s].x) * (bx[s].w - bx[s].y);
    }

    int jb  = q * JQ + w * 32;                     // uniform
    int jfb = 2047 - jb;                           // uniform
    unsigned long long addr = (unsigned long long)rec2d
                            + (unsigned long long)(b * PP + jb) * 32ull;

    unsigned best[4][3];
#pragma unroll
    for (int s = 0; s < 4; ++s) { best[s][0] = 0u; best[s][1] = 0u; best[s][2] = 0u; }

    v8i A0, A1, A2, A3, B0, B1, B2, B3;

#define ISSUE4(R0, R1, R2, R3)                                                 \
    asm volatile("s_load_dwordx8 %0, %1, 0x0"  : "=&s"(R0) : "s"(addr));       \
    asm volatile("s_load_dwordx8 %0, %1, 0x20" : "=&s"(R1) : "s"(addr));       \
    asm volatile("s_load_dwordx8 %0, %1, 0x40" : "=&s"(R2) : "s"(addr));       \
    asm volatile("s_load_dwordx8 %0, %1, 0x60" : "=&s"(R3) : "s"(addr));       \
    addr += 128;

#define DO_J(R, KOFF)                                                          \
    {                                                                          \
        float bjx = __uint_as_float((unsigned)R[0]);                           \
        float bjy = __uint_as_float((unsigned)R[1]);                           \
        float bjz = __uint_as_float((unsigned)R[2]);                           \
        float bjw = __uint_as_float((unsigned)R[3]);                           \
        float aj  = __uint_as_float((unsigned)R[4]);                           \
        unsigned m0 = (unsigned)R[5], m1 = (unsigned)R[6], m2 = (unsigned)R[7];\
        unsigned jf = (unsigned)(jfb - (KOFF));                                \
        _Pragma("unroll")                                                      \
        for (int s = 0; s < 4; ++s) {                                          \
            float lx = fmaxf(bx[s].x, bjx), ly = fmaxf(bx[s].y, bjy);          \
            float rx = fminf(bx[s].z, bjz), ry = fminf(bx[s].w, bjw);          \
            float ww = fmaxf(rx - lx, 0.f), hh = fmaxf(ry - ly, 0.f);          \
            float inter = ww * hh;                                             \
            float uni   = (ax[s] + aj) - inter;                                \
            float iou   = inter * __builtin_amdgcn_rcpf(uni);                  \
            unsigned pk = (__float_as_uint(iou) & HIMASK) | jf;                \
            unsigned k0 = pk & m0, k1 = pk & m1, k2 = pk & m2;                 \
            best[s][0] = best[s][0] > k0 ? best[s][0] : k0;                    \
            best[s][1] = best[s][1] > k1 ? best[s][1] : k1;                    \
            best[s][2] = best[s][2] > k2 ? best[s][2] : k2;                    \
        }                                                                      \
    }

#define BATCH(C0, C1, C2, C3, N0, N1, N2, N3, BASE, DOISSUE)                   \
    asm volatile("s_waitcnt lgkmcnt(0)"                                        \
                 : "+s"(C0), "+s"(C1), "+s"(C2), "+s"(C3));                    \
    __builtin_amdgcn_sched_barrier(0);                                         \
    if (DOISSUE) { ISSUE4(N0, N1, N2, N3) }                                    \
    DO_J(C0, (BASE) + 0) DO_J(C1, (BASE) + 1)                                  \
    DO_J(C2, (BASE) + 2) DO_J(C3, (BASE) + 3)

    ISSUE4(A0, A1, A2, A3)
    BATCH(A0, A1, A2, A3, B0, B1, B2, B3,  0, 1)
    BATCH(B0, B1, B2, B3, A0, A1, A2, A3,  4, 1)
    BATCH(A0, A1, A2, A3, B0, B1, B2, B3,  8, 1)
    BATCH(B0, B1, B2, B3, A0, A1, A2, A3, 12, 1)
    BATCH(A0, A1, A2, A3, B0, B1, B2, B3, 16, 1)
    BATCH(B0, B1, B2, B3, A0, A1, A2, A3, 20, 1)
    BATCH(A0, A1, A2, A3, B0, B1, B2, B3, 24, 1)
    BATCH(B0, B1, B2, B3, A0, A1, A2, A3, 28, 0)

#undef BATCH
#undef DO_J
#undef ISSUE4

#pragma unroll
    for (int s = 0; s < 4; ++s) {
        bestA[0][w][s * 64 + lane] = best[s][0];
        bestA[1][w][s * 64 + lane] = best[s][1];
        bestA[2][w][s * 64 + lane] = best[s][2];
    }
    __syncthreads();

    if (tid < IT) {
#pragma unroll
        for (int c = 0; c < 3; ++c) {
            unsigned m = bestA[c][0][tid];
#pragma unroll
            for (int w2 = 1; w2 < 8; ++w2) {
                unsigned o = bestA[c][w2][tid];
                m = m > o ? m : o;
            }
            qres[(((size_t)b * NQ + q) * 3 + c) * PP + it * IT + tid] = m;
        }
    }

    // ---- fc softmax tail: all operands already in registers ----
#pragma unroll
    for (int r = 0; r < 4; ++r) {
        float a0 = 0.f, a1 = 0.f, a2 = 0.f, a3 = 0.f;
#pragma unroll
        for (int t = 0; t < 2; ++t) {
            float4 x = xin[r][t];
            a0 += x.x * wr[0][t].x + x.y * wr[0][t].y + x.z * wr[0][t].z + x.w * wr[0][t].w;
            a1 += x.x * wr[1][t].x + x.y * wr[1][t].y + x.z * wr[1][t].z + x.w * wr[1][t].w;
            a2 += x.x * wr[2][t].x + x.y * wr[2][t].y + x.z * wr[2][t].z + x.w * wr[2][t].w;
            a3 += x.x * wr[3][t].x + x.y * wr[3][t].y + x.z * wr[3][t].z + x.w * wr[3][t].w;
        }
#pragma unroll
        for (int off = 32; off > 0; off >>= 1) {
            a0 += __shfl_xor(a0, off);
            a1 += __shfl_xor(a1, off);
            a2 += __shfl_xor(a2, off);
            a3 += __shfl_xor(a3, off);
        }
        if (lane == 0) {
            a0 += fc_b[0]; a1 += fc_b[1]; a2 += fc_b[2]; a3 += fc_b[3];
            float m = fmaxf(fmaxf(a0, a1), fmaxf(a2, a3));
            float e0 = expf(a0 - m), e1 = expf(a1 - m);
            float e2 = expf(a2 - m), e3 = expf(a3 - m);
            float inv = 1.0f / (e0 + e1 + e2 + e3);
            ((float4*)out)[row0 + r] = make_float4(e0 * inv, e1 * inv, e2 * inv, e3 * inv);
        }
    }
}

// ---------------------------------------------------------------------------
// K4: merge j-slices + sequential class logic + focal loss; per-(b,it)
// partial sums. 128 blocks x 256 threads.
// ---------------------------------------------------------------------------
__global__ void __launch_bounds__(256) merge_focal_kernel(
    const unsigned* __restrict__ qres, const float* __restrict__ pre_score,
    const int* __restrict__ labels, const float* __restrict__ xr,
    float* __restrict__ partials)
{
    __shared__ float redw[4], redf[4];
    int bt = blockIdx.x;
    int b = bt >> 3, it = bt & 7;
    int tid = threadIdx.x;
    int i = it * IT + tid;

    float I = 0.f, wv = 0.f;
    int target = 3;
#pragma unroll
    for (int c = 0; c < 3; ++c) {
        unsigned k = 0u;
#pragma unroll
        for (int qq = 0; qq < NQ; ++qq) {
            unsigned h = qres[(((size_t)b * NQ + qq) * 3 + c) * PP + i];
            k = k > h ? k : h;   // packed keys globally unique per j
        }
        int   jv    = 2047 - (int)(k & 2047u);
        float bestv = __uint_as_float(k & HIMASK);
        bestv = (labels[b * 3 + c] != 0) ? bestv : -1.0f;
        if (bestv > I) {
            wv = pre_score[((size_t)b * PP + jv) * 3 + c];
            if (bestv > 0.5f && target == 3) target = c;
            I = bestv;
        }
    }
    // focal loss on double-softmaxed scores
    int gi = b * PP + i;
    float4 x4 = ((const float4*)xr)[gi];
    float m = fmaxf(fmaxf(x4.x, x4.y), fmaxf(x4.z, x4.w));
    float e0 = expf(x4.x - m), e1 = expf(x4.y - m), e2 = expf(x4.z - m), e3 = expf(x4.w - m);
    float ssum = e0 + e1 + e2 + e3;
    float et = (target == 0) ? e0 : (target == 1) ? e1 : (target == 2) ? e2 : e3;
    float pt = et / ssum;
    pt = fminf(fmaxf(pt, 1e-7f), 1.0f - 1e-7f);
    float fl = -logf(pt) * (1.0f - pt) * (1.0f - pt);

    float sw = wv, sf = fl;
#pragma unroll
    for (int off = 32; off > 0; off >>= 1) {
        sw += __shfl_down(sw, off);
        sf += __shfl_down(sf, off);
    }
    if ((tid & 63) == 0) { redw[tid >> 6] = sw; redf[tid >> 6] = sf; }
    __syncthreads();
    if (tid == 0) {
        partials[bt * 2 + 0] = redw[0] + redw[1] + redw[2] + redw[3];
        partials[bt * 2 + 1] = redf[0] + redf[1] + redf[2] + redf[3];
    }
}

// ---------------------------------------------------------------------------
// K5: deterministic finalize: loss = mean(w) * mean(floss)
// ---------------------------------------------------------------------------
__global__ void __launch_bounds__(256) finalize_kernel(
    const float* __restrict__ partials, float* __restrict__ out_loss)
{
    __shared__ float swL[256], sfL[256];
    int tid = threadIdx.x;
    float sw = (tid < NBT2) ? partials[2 * tid] : 0.f;
    float sf = (tid < NBT2) ? partials[2 * tid + 1] : 0.f;
    swL[tid] = sw; sfL[tid] = sf;
    __syncthreads();
    for (int s = 128; s > 0; s >>= 1) {
        if (tid < s) { swL[tid] += swL[tid + s]; sfL[tid] += sfL[tid + s]; }
        __syncthreads();
    }
    if (tid == 0)
        out_loss[0] = (swL[0] / (float)NROW) * (sfL[0] / (float)NROW);
}

// ---------------------------------------------------------------------------
extern "C" void kernel_launch(void* const* d_in, const int* in_sizes, int n_in,
                              void* d_out, int out_size, void* d_ws, size_t ws_size,
                              hipStream_t stream)
{
    const float* inputs    = (const float*)d_in[0];
    const float* pre_score = (const float*)d_in[1];
    const int*   labels    = (const int*)d_in[2];
    const float* rois      = (const float*)d_in[3];
    // d_in[4] = num (2048, fixed)
    const float* fc_w      = (const float*)d_in[5];
    const float* fc_b      = (const float*)d_in[6];

    float* out = (float*)d_out;
    char* ws = (char*)d_ws;
    unsigned* qres     = (unsigned*)ws;                     // 3,145,728 B
    uint4*    rec2     = (uint4*)(ws + 3145728);            // 1,048,576 B
    unsigned* cmask    = (unsigned*)(ws + 4194304);         //   393,216 B
    float*    partials = (float*)(ws + 4587520);            //     1,024 B

    cand_kernel<<<BS * 3, 256, 0, stream>>>(pre_score, cmask);
    pack_kernel<<<BS * 8, 256, 0, stream>>>(rois, cmask, rec2);
    fused_kernel<<<NBLK_IOU, 512, 0, stream>>>(rois, (const unsigned*)rec2, qres,
                                               inputs, fc_w, fc_b, out);
    merge_focal_kernel<<<NBT2, 256, 0, stream>>>(qres, pre_score, labels, out, partials);
    finalize_kernel<<<1, 256, 0, stream>>>(partials, out + (size_t)NROW * 4);
}

// Round 18
// 58.631 us; speedup vs baseline: 1.7685x; 1.0636x over previous
//
#include <hip/hip_runtime.h>
#include <math.h>

#define BS   16
#define PP   2048
#define CIN  500
#define NROW (BS * PP)            // 32768
#define JQ   256                  // j's per iou block
#define NQ   8                    // j slices
#define IT   256                  // i's per iou block (4 slots/lane)
#define NIT  8                    // i tiles per batch
#define NBLK_IOU (BS * NIT * NQ)  // 1024
#define NBT2 128
#define HIMASK 0xFFFFF800u

typedef int v8i __attribute__((ext_vector_type(8)));

// ---------------------------------------------------------------------------
// K1: cand — per (b,c): cand = score>0.5, fallback to first-argmax one-hot
// when count<=1. 48 blocks.
// ---------------------------------------------------------------------------
__global__ void __launch_bounds__(256) cand_kernel(
    const float* __restrict__ pre_score, unsigned* __restrict__ cmask)
{
    int bc = blockIdx.x;          // b*3 + c
    int b = bc / 3, c = bc - b * 3;
    int tid = threadIdx.x;
    __shared__ float sv[256];
    __shared__ int   si[256];
    __shared__ int   sn[256];

    float v[8];
#pragma unroll
    for (int t = 0; t < 8; ++t) {
        int j = t * 256 + tid;
        v[t] = pre_score[((size_t)b * PP + j) * 3 + c];
    }
    float bv = -1.0f; int bi = 0; int cnt = 0;
#pragma unroll
    for (int t = 0; t < 8; ++t) {
        int j = t * 256 + tid;
        if (v[t] > 0.5f) cnt++;
        if (v[t] > bv) { bv = v[t]; bi = j; }   // strict > => first max
    }
    sv[tid] = bv; si[tid] = bi; sn[tid] = cnt;
    __syncthreads();
    for (int s2 = 128; s2 > 0; s2 >>= 1) {
        if (tid < s2) {
            float ov = sv[tid + s2]; int oi = si[tid + s2];
            if (ov > sv[tid] || (ov == sv[tid] && oi < si[tid])) { sv[tid] = ov; si[tid] = oi; }
            sn[tid] += sn[tid + s2];
        }
        __syncthreads();
    }
    int total = sn[0];
    int amax  = si[0];
#pragma unroll
    for (int t = 0; t < 8; ++t) {
        int j = t * 256 + tid;
        bool cb = (total <= 1) ? (j == amax) : (v[t] > 0.5f);
        cmask[(size_t)bc * PP + j] = cb ? 0xFFFFFFFFu : 0u;
    }
}

// ---------------------------------------------------------------------------
// K2: pack — 128 blocks, one thread per j: build the 32-B record
// {x1,y1,x2,y2,area,m0,m1,m2}. Pure coalesced load->store.
// ---------------------------------------------------------------------------
__global__ void __launch_bounds__(256) pack_kernel(
    const float* __restrict__ rois, const unsigned* __restrict__ cmask,
    uint4* __restrict__ rec2)
{
    int blk = blockIdx.x;          // b*8 + seg
    int b = blk >> 3, seg = blk & 7;
    int j = seg * 256 + threadIdx.x;
    float4 bx = ((const float4*)(rois + (size_t)b * PP * 4))[j];
    float area = (bx.z - bx.x) * (bx.w - bx.y);
    uint4 lo, hi;
    lo.x = __float_as_uint(bx.x);
    lo.y = __float_as_uint(bx.y);
    lo.z = __float_as_uint(bx.z);
    lo.w = __float_as_uint(bx.w);
    hi.x = __float_as_uint(area);
    hi.y = cmask[((size_t)b * 3 + 0) * PP + j];
    hi.z = cmask[((size_t)b * 3 + 1) * PP + j];
    hi.w = cmask[((size_t)b * 3 + 2) * PP + j];
    rec2[((size_t)b * PP + j) * 2 + 0] = lo;
    rec2[((size_t)b * PP + j) * 2 + 1] = hi;
}

// ---------------------------------------------------------------------------
// K3: fused iou + fc_softmax. 512 thr (8 waves) cover 256 i's (4 slots/lane)
// x 256 j's (SMEM s_load_dwordx8 broadcast, batches of 4, double-buffered).
// NEW: wave-uniform scalar branches on the candidate masks — skip whole j
// when no class is candidate (~12.5%), and per active class m_c==0xFFFFFFFF
// so the AND vanishes (best = max(best, pk)). Exactness: identical keys
// accumulate whenever the mask is set; skipped terms are exactly the zeros.
// fc: reg-held weights + prefetched input rows.
// ---------------------------------------------------------------------------
__global__ void __launch_bounds__(512, 4) fused_kernel(
    const float* __restrict__ rois, const unsigned* __restrict__ rec2d,
    unsigned* __restrict__ qres,
    const float* __restrict__ inputs, const float* __restrict__ fc_w,
    const float* __restrict__ fc_b, float* __restrict__ out)
{
    __shared__ unsigned bestA[3][8][IT];  // 24 KiB
    int bid = blockIdx.x;
    int q   = bid & 7;
    int it  = (bid >> 3) & 7;
    int b   = bid >> 6;
    int tid = threadIdx.x, lane = tid & 63;
    int w   = __builtin_amdgcn_readfirstlane(tid >> 6);   // wave-uniform -> SGPR

    // ---- fc operands: per-lane weight registers + input prefetch ----
    float4 wr[4][2];
#pragma unroll
    for (int c = 0; c < 4; ++c) {
        const float4* wrow = (const float4*)(fc_w + c * CIN);
        wr[c][0] = wrow[lane];
        wr[c][1] = (lane < 61) ? wrow[64 + lane]
                               : make_float4(0.f, 0.f, 0.f, 0.f);
    }
    int row0 = bid * 32 + w * 4;
    int f1 = (lane < 61) ? 64 + lane : 0;   // clamped; weight=0 kills lanes>=61
    float4 xin[4][2];
#pragma unroll
    for (int r = 0; r < 4; ++r) {
        const float4* in4 = (const float4*)(inputs + (size_t)(row0 + r) * CIN);
        xin[r][0] = in4[lane];
        xin[r][1] = in4[f1];
    }

    const float4* rbase = (const float4*)(rois + (size_t)b * PP * 4);
    float4 bx[4];
    float  ax[4];
#pragma unroll
    for (int s = 0; s < 4; ++s) {
        bx[s] = rbase[it * IT + s * 64 + lane];
        ax[s] = (bx[s].z - bx[s].x) * (bx[s].w - bx[s].y);
    }

    int jb  = q * JQ + w * 32;                     // uniform
    int jfb = 2047 - jb;                           // uniform
    unsigned long long addr = (unsigned long long)rec2d
                            + (unsigned long long)(b * PP + jb) * 32ull;

    unsigned best[4][3];
#pragma unroll
    for (int s = 0; s < 4; ++s) { best[s][0] = 0u; best[s][1] = 0u; best[s][2] = 0u; }

    v8i A0, A1, A2, A3, B0, B1, B2, B3;

#define ISSUE4(R0, R1, R2, R3)                                                 \
    asm volatile("s_load_dwordx8 %0, %1, 0x0"  : "=&s"(R0) : "s"(addr));       \
    asm volatile("s_load_dwordx8 %0, %1, 0x20" : "=&s"(R1) : "s"(addr));       \
    asm volatile("s_load_dwordx8 %0, %1, 0x40" : "=&s"(R2) : "s"(addr));       \
    asm volatile("s_load_dwordx8 %0, %1, 0x60" : "=&s"(R3) : "s"(addr));       \
    addr += 128;

#define DO_J(R, KOFF)                                                          \
    {                                                                          \
        unsigned m0 = (unsigned)R[5], m1 = (unsigned)R[6], m2 = (unsigned)R[7];\
        if ((m0 | m1 | m2) != 0u) {   /* wave-uniform: scalar branch */        \
            float bjx = __uint_as_float((unsigned)R[0]);                       \
            float bjy = __uint_as_float((unsigned)R[1]);                       \
            float bjz = __uint_as_float((unsigned)R[2]);                       \
            float bjw = __uint_as_float((unsigned)R[3]);                       \
            float aj  = __uint_as_float((unsigned)R[4]);                       \
            unsigned jf = (unsigned)(jfb - (KOFF));                            \
            unsigned pk0, pk1, pk2, pk3;                                       \
            {                                                                  \
                float lx = fmaxf(bx[0].x, bjx), ly = fmaxf(bx[0].y, bjy);      \
                float rx = fminf(bx[0].z, bjz), ry = fminf(bx[0].w, bjw);      \
                float ww = fmaxf(rx - lx, 0.f), hh = fmaxf(ry - ly, 0.f);      \
                float inter = ww * hh;                                         \
                float uni   = (ax[0] + aj) - inter;                            \
                float iou   = inter * __builtin_amdgcn_rcpf(uni);              \
                pk0 = (__float_as_uint(iou) & HIMASK) | jf;                    \
            }                                                                  \
            {                                                                  \
                float lx = fmaxf(bx[1].x, bjx), ly = fmaxf(bx[1].y, bjy);      \
                float rx = fminf(bx[1].z, bjz), ry = fminf(bx[1].w, bjw);      \
                float ww = fmaxf(rx - lx, 0.f), hh = fmaxf(ry - ly, 0.f);      \
                float inter = ww * hh;                                         \
                float uni   = (ax[1] + aj) - inter;                            \
                float iou   = inter * __builtin_amdgcn_rcpf(uni);              \
                pk1 = (__float_as_uint(iou) & HIMASK) | jf;                    \
            }                                                                  \
            {                                                                  \
                float lx = fmaxf(bx[2].x, bjx), ly = fmaxf(bx[2].y, bjy);      \
                float rx = fminf(bx[2].z, bjz), ry = fminf(bx[2].w, bjw);      \
                float ww = fmaxf(rx - lx, 0.f), hh = fmaxf(ry - ly, 0.f);      \
                float inter = ww * hh;                                         \
                float uni   = (ax[2] + aj) - inter;                            \
                float iou   = inter * __builtin_amdgcn_rcpf(uni);              \
                pk2 = (__float_as_uint(iou) & HIMASK) | jf;                    \
            }                                                                  \
            {                                                                  \
                float lx = fmaxf(bx[3].x, bjx), ly = fmaxf(bx[3].y, bjy);      \
                float rx = fminf(bx[3].z, bjz), ry = fminf(bx[3].w, bjw);      \
                float ww = fmaxf(rx - lx, 0.f), hh = fmaxf(ry - ly, 0.f);      \
                float inter = ww * hh;                                         \
                float uni   = (ax[3] + aj) - inter;                            \
                float iou   = inter * __builtin_amdgcn_rcpf(uni);              \
                pk3 = (__float_as_uint(iou) & HIMASK) | jf;                    \
            }                                                                  \
            if (m0 != 0u) {           /* m0 == all-ones: AND drops out */      \
                best[0][0] = best[0][0] > pk0 ? best[0][0] : pk0;              \
                best[1][0] = best[1][0] > pk1 ? best[1][0] : pk1;              \
                best[2][0] = best[2][0] > pk2 ? best[2][0] : pk2;              \
                best[3][0] = best[3][0] > pk3 ? best[3][0] : pk3;              \
            }                                                                  \
            if (m1 != 0u) {                                                    \
                best[0][1] = best[0][1] > pk0 ? best[0][1] : pk0;              \
                best[1][1] = best[1][1] > pk1 ? best[1][1] : pk1;              \
                best[2][1] = best[2][1] > pk2 ? best[2][1] : pk2;              \
                best[3][1] = best[3][1] > pk3 ? best[3][1] : pk3;              \
            }                                                                  \
            if (m2 != 0u) {                                                    \
                best[0][2] = best[0][2] > pk0 ? best[0][2] : pk0;              \
                best[1][2] = best[1][2] > pk1 ? best[1][2] : pk1;              \
                best[2][2] = best[2][2] > pk2 ? best[2][2] : pk2;              \
                best[3][2] = best[3][2] > pk3 ? best[3][2] : pk3;              \
            }                                                                  \
        }                                                                      \
    }

#define BATCH(C0, C1, C2, C3, N0, N1, N2, N3, BASE, DOISSUE)                   \
    asm volatile("s_waitcnt lgkmcnt(0)"                                        \
                 : "+s"(C0), "+s"(C1), "+s"(C2), "+s"(C3));                    \
    __builtin_amdgcn_sched_barrier(0);                                         \
    if (DOISSUE) { ISSUE4(N0, N1, N2, N3) }                                    \
    DO_J(C0, (BASE) + 0) DO_J(C1, (BASE) + 1)                                  \
    DO_J(C2, (BASE) + 2) DO_J(C3, (BASE) + 3)

    ISSUE4(A0, A1, A2, A3)
    BATCH(A0, A1, A2, A3, B0, B1, B2, B3,  0, 1)
    BATCH(B0, B1, B2, B3, A0, A1, A2, A3,  4, 1)
    BATCH(A0, A1, A2, A3, B0, B1, B2, B3,  8, 1)
    BATCH(B0, B1, B2, B3, A0, A1, A2, A3, 12, 1)
    BATCH(A0, A1, A2, A3, B0, B1, B2, B3, 16, 1)
    BATCH(B0, B1, B2, B3, A0, A1, A2, A3, 20, 1)
    BATCH(A0, A1, A2, A3, B0, B1, B2, B3, 24, 1)
    BATCH(B0, B1, B2, B3, A0, A1, A2, A3, 28, 0)

#undef BATCH
#undef DO_J
#undef ISSUE4

#pragma unroll
    for (int s = 0; s < 4; ++s) {
        bestA[0][w][s * 64 + lane] = best[s][0];
        bestA[1][w][s * 64 + lane] = best[s][1];
        bestA[2][w][s * 64 + lane] = best[s][2];
    }
    __syncthreads();

    if (tid < IT) {
#pragma unroll
        for (int c = 0; c < 3; ++c) {
            unsigned m = bestA[c][0][tid];
#pragma unroll
            for (int w2 = 1; w2 < 8; ++w2) {
                unsigned o = bestA[c][w2][tid];
                m = m > o ? m : o;
            }
            qres[(((size_t)b * NQ + q) * 3 + c) * PP + it * IT + tid] = m;
        }
    }

    // ---- fc softmax tail: all operands already in registers ----
#pragma unroll
    for (int r = 0; r < 4; ++r) {
        float a0 = 0.f, a1 = 0.f, a2 = 0.f, a3 = 0.f;
#pragma unroll
        for (int t = 0; t < 2; ++t) {
            float4 x = xin[r][t];
            a0 += x.x * wr[0][t].x + x.y * wr[0][t].y + x.z * wr[0][t].z + x.w * wr[0][t].w;
            a1 += x.x * wr[1][t].x + x.y * wr[1][t].y + x.z * wr[1][t].z + x.w * wr[1][t].w;
            a2 += x.x * wr[2][t].x + x.y * wr[2][t].y + x.z * wr[2][t].z + x.w * wr[2][t].w;
            a3 += x.x * wr[3][t].x + x.y * wr[3][t].y + x.z * wr[3][t].z + x.w * wr[3][t].w;
        }
#pragma unroll
        for (int off = 32; off > 0; off >>= 1) {
            a0 += __shfl_xor(a0, off);
            a1 += __shfl_xor(a1, off);
            a2 += __shfl_xor(a2, off);
            a3 += __shfl_xor(a3, off);
        }
        if (lane == 0) {
            a0 += fc_b[0]; a1 += fc_b[1]; a2 += fc_b[2]; a3 += fc_b[3];
            float m = fmaxf(fmaxf(a0, a1), fmaxf(a2, a3));
            float e0 = expf(a0 - m), e1 = expf(a1 - m);
            float e2 = expf(a2 - m), e3 = expf(a3 - m);
            float inv = 1.0f / (e0 + e1 + e2 + e3);
            ((float4*)out)[row0 + r] = make_float4(e0 * inv, e1 * inv, e2 * inv, e3 * inv);
        }
    }
}

// ---------------------------------------------------------------------------
// K4: merge j-slices + sequential class logic + focal loss; per-(b,it)
// partial sums. 128 blocks x 256 threads.
// ---------------------------------------------------------------------------
__global__ void __launch_bounds__(256) merge_focal_kernel(
    const unsigned* __restrict__ qres, const float* __restrict__ pre_score,
    const int* __restrict__ labels, const float* __restrict__ xr,
    float* __restrict__ partials)
{
    __shared__ float redw[4], redf[4];
    int bt = blockIdx.x;
    int b = bt >> 3, it = bt & 7;
    int tid = threadIdx.x;
    int i = it * IT + tid;

    float I = 0.f, wv = 0.f;
    int target = 3;
#pragma unroll
    for (int c = 0; c < 3; ++c) {
        unsigned k = 0u;
#pragma unroll
        for (int qq = 0; qq < NQ; ++qq) {
            unsigned h = qres[(((size_t)b * NQ + qq) * 3 + c) * PP + i];
            k = k > h ? k : h;   // packed keys globally unique per j
        }
        int   jv    = 2047 - (int)(k & 2047u);
        float bestv = __uint_as_float(k & HIMASK);
        bestv = (labels[b * 3 + c] != 0) ? bestv : -1.0f;
        if (bestv > I) {
            wv = pre_score[((size_t)b * PP + jv) * 3 + c];
            if (bestv > 0.5f && target == 3) target = c;
            I = bestv;
        }
    }
    // focal loss on double-softmaxed scores
    int gi = b * PP + i;
    float4 x4 = ((const float4*)xr)[gi];
    float m = fmaxf(fmaxf(x4.x, x4.y), fmaxf(x4.z, x4.w));
    float e0 = expf(x4.x - m), e1 = expf(x4.y - m), e2 = expf(x4.z - m), e3 = expf(x4.w - m);
    float ssum = e0 + e1 + e2 + e3;
    float et = (target == 0) ? e0 : (target == 1) ? e1 : (target == 2) ? e2 : e3;
    float pt = et / ssum;
    pt = fminf(fmaxf(pt, 1e-7f), 1.0f - 1e-7f);
    float fl = -logf(pt) * (1.0f - pt) * (1.0f - pt);

    float sw = wv, sf = fl;
#pragma unroll
    for (int off = 32; off > 0; off >>= 1) {
        sw += __shfl_down(sw, off);
        sf += __shfl_down(sf, off);
    }
    if ((tid & 63) == 0) { redw[tid >> 6] = sw; redf[tid >> 6] = sf; }
    __syncthreads();
    if (tid == 0) {
        partials[bt * 2 + 0] = redw[0] + redw[1] + redw[2] + redw[3];
        partials[bt * 2 + 1] = redf[0] + redf[1] + redf[2] + redf[3];
    }
}

// ---------------------------------------------------------------------------
// K5: deterministic finalize: loss = mean(w) * mean(floss)
// ---------------------------------------------------------------------------
__global__ void __launch_bounds__(256) finalize_kernel(
    const float* __restrict__ partials, float* __restrict__ out_loss)
{
    __shared__ float swL[256], sfL[256];
    int tid = threadIdx.x;
    float sw = (tid < NBT2) ? partials[2 * tid] : 0.f;
    float sf = (tid < NBT2) ? partials[2 * tid + 1] : 0.f;
    swL[tid] = sw; sfL[tid] = sf;
    __syncthreads();
    for (int s = 128; s > 0; s >>= 1) {
        if (tid < s) { swL[tid] += swL[tid + s]; sfL[tid] += sfL[tid + s]; }
        __syncthreads();
    }
    if (tid == 0)
        out_loss[0] = (swL[0] / (float)NROW) * (sfL[0] / (float)NROW);
}

// ---------------------------------------------------------------------------
extern "C" void kernel_launch(void* const* d_in, const int* in_sizes, int n_in,
                              void* d_out, int out_size, void* d_ws, size_t ws_size,
                              hipStream_t stream)
{
    const float* inputs    = (const float*)d_in[0];
    const float* pre_score = (const float*)d_in[1];
    const int*   labels    = (const int*)d_in[2];
    const float* rois      = (const float*)d_in[3];
    // d_in[4] = num (2048, fixed)
    const float* fc_w      = (const float*)d_in[5];
    const float* fc_b      = (const float*)d_in[6];

    float* out = (float*)d_out;
    char* ws = (char*)d_ws;
    unsigned* qres     = (unsigned*)ws;                     // 3,145,728 B
    uint4*    rec2     = (uint4*)(ws + 3145728);            // 1,048,576 B
    unsigned* cmask    = (unsigned*)(ws + 4194304);         //   393,216 B
    float*    partials = (float*)(ws + 4587520);            //     1,024 B

    cand_kernel<<<BS * 3, 256, 0, stream>>>(pre_score, cmask);
    pack_kernel<<<BS * 8, 256, 0, stream>>>(rois, cmask, rec2);
    fused_kernel<<<NBLK_IOU, 512, 0, stream>>>(rois, (const unsigned*)rec2, qres,
                                               inputs, fc_w, fc_b, out);
    merge_focal_kernel<<<NBT2, 256, 0, stream>>>(qres, pre_score, labels, out, partials);
    finalize_kernel<<<1, 256, 0, stream>>>(partials, out + (size_t)NROW * 4);
}

// Round 20
// 57.250 us; speedup vs baseline: 1.8111x; 1.0241x over previous
//
#include <hip/hip_runtime.h>
#include <math.h>

#define BS   16
#define PP   2048
#define CIN  500
#define NROW (BS * PP)            // 32768
#define JQ   256                  // j's per iou block
#define NQ   8                    // j slices
#define IT   256                  // i's per iou block (4 slots/lane)
#define NIT  8                    // i tiles per batch
#define NBLK_IOU (BS * NIT * NQ)  // 1024
#define NBT2 128
#define HIMASK 0xFFFFF800u

typedef int v8i __attribute__((ext_vector_type(8)));

// ---------------------------------------------------------------------------
// K1: cand — per (b,c): cand = score>0.5, fallback to first-argmax one-hot
// when count<=1. 48 blocks.
// ---------------------------------------------------------------------------
__global__ void __launch_bounds__(256) cand_kernel(
    const float* __restrict__ pre_score, unsigned* __restrict__ cmask)
{
    int bc = blockIdx.x;          // b*3 + c
    int b = bc / 3, c = bc - b * 3;
    int tid = threadIdx.x;
    __shared__ float sv[256];
    __shared__ int   si[256];
    __shared__ int   sn[256];

    float v[8];
#pragma unroll
    for (int t = 0; t < 8; ++t) {
        int j = t * 256 + tid;
        v[t] = pre_score[((size_t)b * PP + j) * 3 + c];
    }
    float bv = -1.0f; int bi = 0; int cnt = 0;
#pragma unroll
    for (int t = 0; t < 8; ++t) {
        int j = t * 256 + tid;
        if (v[t] > 0.5f) cnt++;
        if (v[t] > bv) { bv = v[t]; bi = j; }   // strict > => first max
    }
    sv[tid] = bv; si[tid] = bi; sn[tid] = cnt;
    __syncthreads();
    for (int s2 = 128; s2 > 0; s2 >>= 1) {
        if (tid < s2) {
            float ov = sv[tid + s2]; int oi = si[tid + s2];
            if (ov > sv[tid] || (ov == sv[tid] && oi < si[tid])) { sv[tid] = ov; si[tid] = oi; }
            sn[tid] += sn[tid + s2];
        }
        __syncthreads();
    }
    int total = sn[0];
    int amax  = si[0];
#pragma unroll
    for (int t = 0; t < 8; ++t) {
        int j = t * 256 + tid;
        bool cb = (total <= 1) ? (j == amax) : (v[t] > 0.5f);
        cmask[(size_t)bc * PP + j] = cb ? 0xFFFFFFFFu : 0u;
    }
}

// ---------------------------------------------------------------------------
// K2: pack — 128 blocks, one thread per j: build the 32-B record
// {x1,y1,x2,y2,area,m0,m1,m2}, with m_c additionally ANDed by labels[b,c].
// Exact: a label-off class can never update in the merge (bestv=-1 < I>=0),
// and zeroed masks give keys=0 which also never update. Raises the fused
// kernel's wave-uniform whole-j skip rate from ~12.5% to ~42%.
// ---------------------------------------------------------------------------
__global__ void __launch_bounds__(256) pack_kernel(
    const float* __restrict__ rois, const unsigned* __restrict__ cmask,
    const int* __restrict__ labels, uint4* __restrict__ rec2)
{
    int blk = blockIdx.x;          // b*8 + seg
    int b = blk >> 3, seg = blk & 7;
    int j = seg * 256 + threadIdx.x;
    unsigned l0 = (labels[b * 3 + 0] != 0) ? 0xFFFFFFFFu : 0u;
    unsigned l1 = (labels[b * 3 + 1] != 0) ? 0xFFFFFFFFu : 0u;
    unsigned l2 = (labels[b * 3 + 2] != 0) ? 0xFFFFFFFFu : 0u;
    float4 bx = ((const float4*)(rois + (size_t)b * PP * 4))[j];
    float area = (bx.z - bx.x) * (bx.w - bx.y);
    uint4 lo, hi;
    lo.x = __float_as_uint(bx.x);
    lo.y = __float_as_uint(bx.y);
    lo.z = __float_as_uint(bx.z);
    lo.w = __float_as_uint(bx.w);
    hi.x = __float_as_uint(area);
    hi.y = cmask[((size_t)b * 3 + 0) * PP + j] & l0;
    hi.z = cmask[((size_t)b * 3 + 1) * PP + j] & l1;
    hi.w = cmask[((size_t)b * 3 + 2) * PP + j] & l2;
    rec2[((size_t)b * PP + j) * 2 + 0] = lo;
    rec2[((size_t)b * PP + j) * 2 + 1] = hi;
}

// ---------------------------------------------------------------------------
// K3: fused iou + fc_softmax (R18 structure, known-good). 512 thr (8 waves)
// cover 256 i's (4 slots/lane) x 256 j's (SMEM s_load_dwordx8 broadcast,
// batches of 4, double-buffered). Wave-uniform scalar branches on candidate
// masks (now label-folded): skip whole j when no active class; per active
// class m_c==all-ones so the AND drops out. Packed-key argmax — exact
// first-max tie-break. fc: reg-held weights + prefetched input rows.
// ---------------------------------------------------------------------------
__global__ void __launch_bounds__(512, 4) fused_kernel(
    const float* __restrict__ rois, const unsigned* __restrict__ rec2d,
    unsigned* __restrict__ qres,
    const float* __restrict__ inputs, const float* __restrict__ fc_w,
    const float* __restrict__ fc_b, float* __restrict__ out)
{
    __shared__ unsigned bestA[3][8][IT];  // 24 KiB
    int bid = blockIdx.x;
    int q   = bid & 7;
    int it  = (bid >> 3) & 7;
    int b   = bid >> 6;
    int tid = threadIdx.x, lane = tid & 63;
    int w   = __builtin_amdgcn_readfirstlane(tid >> 6);   // wave-uniform -> SGPR

    // ---- fc operands: per-lane weight registers + input prefetch ----
    float4 wr[4][2];
#pragma unroll
    for (int c = 0; c < 4; ++c) {
        const float4* wrow = (const float4*)(fc_w + c * CIN);
        wr[c][0] = wrow[lane];
        wr[c][1] = (lane < 61) ? wrow[64 + lane]
                               : make_float4(0.f, 0.f, 0.f, 0.f);
    }
    int row0 = bid * 32 + w * 4;
    int f1 = (lane < 61) ? 64 + lane : 0;   // clamped; weight=0 kills lanes>=61
    float4 xin[4][2];
#pragma unroll
    for (int r = 0; r < 4; ++r) {
        const float4* in4 = (const float4*)(inputs + (size_t)(row0 + r) * CIN);
        xin[r][0] = in4[lane];
        xin[r][1] = in4[f1];
    }

    const float4* rbase = (const float4*)(rois + (size_t)b * PP * 4);
    float4 bx[4];
    float  ax[4];
#pragma unroll
    for (int s = 0; s < 4; ++s) {
        bx[s] = rbase[it * IT + s * 64 + lane];
        ax[s] = (bx[s].z - bx[s].x) * (bx[s].w - bx[s].y);
    }

    int jb  = q * JQ + w * 32;                     // uniform
    int jfb = 2047 - jb;                           // uniform
    unsigned long long addr = (unsigned long long)rec2d
                            + (unsigned long long)(b * PP + jb) * 32ull;

    unsigned best[4][3];
#pragma unroll
    for (int s = 0; s < 4; ++s) { best[s][0] = 0u; best[s][1] = 0u; best[s][2] = 0u; }

    v8i A0, A1, A2, A3, B0, B1, B2, B3;

#define ISSUE4(R0, R1, R2, R3)                                                 \
    asm volatile("s_load_dwordx8 %0, %1, 0x0"  : "=&s"(R0) : "s"(addr));       \
    asm volatile("s_load_dwordx8 %0, %1, 0x20" : "=&s"(R1) : "s"(addr));       \
    asm volatile("s_load_dwordx8 %0, %1, 0x40" : "=&s"(R2) : "s"(addr));       \
    asm volatile("s_load_dwordx8 %0, %1, 0x60" : "=&s"(R3) : "s"(addr));       \
    addr += 128;

#define DO_J(R, KOFF)                                                          \
    {                                                                          \
        unsigned m0 = (unsigned)R[5], m1 = (unsigned)R[6], m2 = (unsigned)R[7];\
        if ((m0 | m1 | m2) != 0u) {   /* wave-uniform: scalar branch */        \
            float bjx = __uint_as_float((unsigned)R[0]);                       \
            float bjy = __uint_as_float((unsigned)R[1]);                       \
            float bjz = __uint_as_float((unsigned)R[2]);                       \
            float bjw = __uint_as_float((unsigned)R[3]);                       \
            float aj  = __uint_as_float((unsigned)R[4]);                       \
            unsigned jf = (unsigned)(jfb - (KOFF));                            \
            unsigned pk0, pk1, pk2, pk3;                                       \
            {                                                                  \
                float lx = fmaxf(bx[0].x, bjx), ly = fmaxf(bx[0].y, bjy);      \
                float rx = fminf(bx[0].z, bjz), ry = fminf(bx[0].w, bjw);      \
                float ww = fmaxf(rx - lx, 0.f), hh = fmaxf(ry - ly, 0.f);      \
                float inter = ww * hh;                                         \
                float uni   = (ax[0] + aj) - inter;                            \
                float iou   = inter * __builtin_amdgcn_rcpf(uni);              \
                pk0 = (__float_as_uint(iou) & HIMASK) | jf;                    \
            }                                                                  \
            {                                                                  \
                float lx = fmaxf(bx[1].x, bjx), ly = fmaxf(bx[1].y, bjy);      \
                float rx = fminf(bx[1].z, bjz), ry = fminf(bx[1].w, bjw);      \
                float ww = fmaxf(rx - lx, 0.f), hh = fmaxf(ry - ly, 0.f);      \
                float inter = ww * hh;                                         \
                float uni   = (ax[1] + aj) - inter;                            \
                float iou   = inter * __builtin_amdgcn_rcpf(uni);              \
                pk1 = (__float_as_uint(iou) & HIMASK) | jf;                    \
            }                                                                  \
            {                                                                  \
                float lx = fmaxf(bx[2].x, bjx), ly = fmaxf(bx[2].y, bjy);      \
                float rx = fminf(bx[2].z, bjz), ry = fminf(bx[2].w, bjw);      \
                float ww = fmaxf(rx - lx, 0.f), hh = fmaxf(ry - ly, 0.f);      \
                float inter = ww * hh;                                         \
                float uni   = (ax[2] + aj) - inter;                            \
                float iou   = inter * __builtin_amdgcn_rcpf(uni);              \
                pk2 = (__float_as_uint(iou) & HIMASK) | jf;                    \
            }                                                                  \
            {                                                                  \
                float lx = fmaxf(bx[3].x, bjx), ly = fmaxf(bx[3].y, bjy);      \
                float rx = fminf(bx[3].z, bjz), ry = fminf(bx[3].w, bjw);      \
                float ww = fmaxf(rx - lx, 0.f), hh = fmaxf(ry - ly, 0.f);      \
                float inter = ww * hh;                                         \
                float uni   = (ax[3] + aj) - inter;                            \
                float iou   = inter * __builtin_amdgcn_rcpf(uni);              \
                pk3 = (__float_as_uint(iou) & HIMASK) | jf;                    \
            }                                                                  \
            if (m0 != 0u) {           /* m0 == all-ones: AND drops out */      \
                best[0][0] = best[0][0] > pk0 ? best[0][0] : pk0;              \
                best[1][0] = best[1][0] > pk1 ? best[1][0] : pk1;              \
                best[2][0] = best[2][0] > pk2 ? best[2][0] : pk2;              \
                best[3][0] = best[3][0] > pk3 ? best[3][0] : pk3;              \
            }                                                                  \
            if (m1 != 0u) {                                                    \
                best[0][1] = best[0][1] > pk0 ? best[0][1] : pk0;              \
                best[1][1] = best[1][1] > pk1 ? best[1][1] : pk1;              \
                best[2][1] = best[2][1] > pk2 ? best[2][1] : pk2;              \
                best[3][1] = best[3][1] > pk3 ? best[3][1] : pk3;              \
            }                                                                  \
            if (m2 != 0u) {                                                    \
                best[0][2] = best[0][2] > pk0 ? best[0][2] : pk0;              \
                best[1][2] = best[1][2] > pk1 ? best[1][2] : pk1;              \
                best[2][2] = best[2][2] > pk2 ? best[2][2] : pk2;              \
                best[3][2] = best[3][2] > pk3 ? best[3][2] : pk3;              \
            }                                                                  \
        }                                                                      \
    }

#define BATCH(C0, C1, C2, C3, N0, N1, N2, N3, BASE, DOISSUE)                   \
    asm volatile("s_waitcnt lgkmcnt(0)"                                        \
                 : "+s"(C0), "+s"(C1), "+s"(C2), "+s"(C3));                    \
    __builtin_amdgcn_sched_barrier(0);                                         \
    if (DOISSUE) { ISSUE4(N0, N1, N2, N3) }                                    \
    DO_J(C0, (BASE) + 0) DO_J(C1, (BASE) + 1)                                  \
    DO_J(C2, (BASE) + 2) DO_J(C3, (BASE) + 3)

    ISSUE4(A0, A1, A2, A3)
    BATCH(A0, A1, A2, A3, B0, B1, B2, B3,  0, 1)
    BATCH(B0, B1, B2, B3, A0, A1, A2, A3,  4, 1)
    BATCH(A0, A1, A2, A3, B0, B1, B2, B3,  8, 1)
    BATCH(B0, B1, B2, B3, A0, A1, A2, A3, 12, 1)
    BATCH(A0, A1, A2, A3, B0, B1, B2, B3, 16, 1)
    BATCH(B0, B1, B2, B3, A0, A1, A2, A3, 20, 1)
    BATCH(A0, A1, A2, A3, B0, B1, B2, B3, 24, 1)
    BATCH(B0, B1, B2, B3, A0, A1, A2, A3, 28, 0)

#undef BATCH
#undef DO_J
#undef ISSUE4

#pragma unroll
    for (int s = 0; s < 4; ++s) {
        bestA[0][w][s * 64 + lane] = best[s][0];
        bestA[1][w][s * 64 + lane] = best[s][1];
        bestA[2][w][s * 64 + lane] = best[s][2];
    }
    __syncthreads();

    if (tid < IT) {
#pragma unroll
        for (int c = 0; c < 3; ++c) {
            unsigned m = bestA[c][0][tid];
#pragma unroll
            for (int w2 = 1; w2 < 8; ++w2) {
                unsigned o = bestA[c][w2][tid];
                m = m > o ? m : o;
            }
            qres[(((size_t)b * NQ + q) * 3 + c) * PP + it * IT + tid] = m;
        }
    }

    // ---- fc softmax tail: all operands already in registers ----
#pragma unroll
    for (int r = 0; r < 4; ++r) {
        float a0 = 0.f, a1 = 0.f, a2 = 0.f, a3 = 0.f;
#pragma unroll
        for (int t = 0; t < 2; ++t) {
            float4 x = xin[r][t];
            a0 += x.x * wr[0][t].x + x.y * wr[0][t].y + x.z * wr[0][t].z + x.w * wr[0][t].w;
            a1 += x.x * wr[1][t].x + x.y * wr[1][t].y + x.z * wr[1][t].z + x.w * wr[1][t].w;
            a2 += x.x * wr[2][t].x + x.y * wr[2][t].y + x.z * wr[2][t].z + x.w * wr[2][t].w;
            a3 += x.x * wr[3][t].x + x.y * wr[3][t].y + x.z * wr[3][t].z + x.w * wr[3][t].w;
        }
#pragma unroll
        for (int off = 32; off > 0; off >>= 1) {
            a0 += __shfl_xor(a0, off);
            a1 += __shfl_xor(a1, off);
            a2 += __shfl_xor(a2, off);
            a3 += __shfl_xor(a3, off);
        }
        if (lane == 0) {
            a0 += fc_b[0]; a1 += fc_b[1]; a2 += fc_b[2]; a3 += fc_b[3];
            float m = fmaxf(fmaxf(a0, a1), fmaxf(a2, a3));
            float e0 = expf(a0 - m), e1 = expf(a1 - m);
            float e2 = expf(a2 - m), e3 = expf(a3 - m);
            float inv = 1.0f / (e0 + e1 + e2 + e3);
            ((float4*)out)[row0 + r] = make_float4(e0 * inv, e1 * inv, e2 * inv, e3 * inv);
        }
    }
}

// ---------------------------------------------------------------------------
// K4: merge j-slices + sequential class logic + focal loss; per-(b,it)
// partial sums. 128 blocks x 256 threads.
// ---------------------------------------------------------------------------
__global__ void __launch_bounds__(256) merge_focal_kernel(
    const unsigned* __restrict__ qres, const float* __restrict__ pre_score,
    const int* __restrict__ labels, const float* __restrict__ xr,
    float* __restrict__ partials)
{
    __shared__ float redw[4], redf[4];
    int bt = blockIdx.x;
    int b = bt >> 3, it = bt & 7;
    int tid = threadIdx.x;
    int i = it * IT + tid;

    float I = 0.f, wv = 0.f;
    int target = 3;
#pragma unroll
    for (int c = 0; c < 3; ++c) {
        unsigned k = 0u;
#pragma unroll
        for (int qq = 0; qq < NQ; ++qq) {
            unsigned h = qres[(((size_t)b * NQ + qq) * 3 + c) * PP + i];
            k = k > h ? k : h;   // packed keys globally unique per j
        }
        int   jv    = 2047 - (int)(k & 2047u);
        float bestv = __uint_as_float(k & HIMASK);
        bestv = (labels[b * 3 + c] != 0) ? bestv : -1.0f;
        if (bestv > I) {
            wv = pre_score[((size_t)b * PP + jv) * 3 + c];
            if (bestv > 0.5f && target == 3) target = c;
            I = bestv;
        }
    }
    // focal loss on double-softmaxed scores
    int gi = b * PP + i;
    float4 x4 = ((const float4*)xr)[gi];
    float m = fmaxf(fmaxf(x4.x, x4.y), fmaxf(x4.z, x4.w));
    float e0 = expf(x4.x - m), e1 = expf(x4.y - m), e2 = expf(x4.z - m), e3 = expf(x4.w - m);
    float ssum = e0 + e1 + e2 + e3;
    float et = (target == 0) ? e0 : (target == 1) ? e1 : (target == 2) ? e2 : e3;
    float pt = et / ssum;
    pt = fminf(fmaxf(pt, 1e-7f), 1.0f - 1e-7f);
    float fl = -logf(pt) * (1.0f - pt) * (1.0f - pt);

    float sw = wv, sf = fl;
#pragma unroll
    for (int off = 32; off > 0; off >>= 1) {
        sw += __shfl_down(sw, off);
        sf += __shfl_down(sf, off);
    }
    if ((tid & 63) == 0) { redw[tid >> 6] = sw; redf[tid >> 6] = sf; }
    __syncthreads();
    if (tid == 0) {
        partials[bt * 2 + 0] = redw[0] + redw[1] + redw[2] + redw[3];
        partials[bt * 2 + 1] = redf[0] + redf[1] + redf[2] + redf[3];
    }
}

// ---------------------------------------------------------------------------
// K5: deterministic finalize: loss = mean(w) * mean(floss)
// ---------------------------------------------------------------------------
__global__ void __launch_bounds__(256) finalize_kernel(
    const float* __restrict__ partials, float* __restrict__ out_loss)
{
    __shared__ float swL[256], sfL[256];
    int tid = threadIdx.x;
    float sw = (tid < NBT2) ? partials[2 * tid] : 0.f;
    float sf = (tid < NBT2) ? partials[2 * tid + 1] : 0.f;
    swL[tid] = sw; sfL[tid] = sf;
    __syncthreads();
    for (int s = 128; s > 0; s >>= 1) {
        if (tid < s) { swL[tid] += swL[tid + s]; sfL[tid] += sfL[tid + s]; }
        __syncthreads();
    }
    if (tid == 0)
        out_loss[0] = (swL[0] / (float)NROW) * (sfL[0] / (float)NROW);
}

// ---------------------------------------------------------------------------
extern "C" void kernel_launch(void* const* d_in, const int* in_sizes, int n_in,
                              void* d_out, int out_size, void* d_ws, size_t ws_size,
                              hipStream_t stream)
{
    const float* inputs    = (const float*)d_in[0];
    const float* pre_score = (const float*)d_in[1];
    const int*   labels    = (const int*)d_in[2];
    const float* rois      = (const float*)d_in[3];
    // d_in[4] = num (2048, fixed)
    const float* fc_w      = (const float*)d_in[5];
    const float* fc_b      = (const float*)d_in[6];

    float* out = (float*)d_out;
    char* ws = (char*)d_ws;
    unsigned* qres     = (unsigned*)ws;                     // 3,145,728 B
    uint4*    rec2     = (uint4*)(ws + 3145728);            // 1,048,576 B
    unsigned* cmask    = (unsigned*)(ws + 4194304);         //   393,216 B
    float*    partials = (float*)(ws + 4587520);            //     1,024 B

    cand_kernel<<<BS * 3, 256, 0, stream>>>(pre_score, cmask);
    pack_kernel<<<BS * 8, 256, 0, stream>>>(rois, cmask, labels, rec2);
    fused_kernel<<<NBLK_IOU, 512, 0, stream>>>(rois, (const unsigned*)rec2, qres,
                                               inputs, fc_w, fc_b, out);
    merge_focal_kernel<<<NBT2, 256, 0, stream>>>(qres, pre_score, labels, out, partials);
    finalize_kernel<<<1, 256, 0, stream>>>(partials, out + (size_t)NROW * 4);
}